// Round 1
// baseline (671.494 us; speedup 1.0000x reference)
//
#include <hip/hip_runtime.h>
#include <math.h>

#define NN 20000
#define EE 400000
#define FIN 256
#define HH 16
#define CC 32
#define HC 512    // H*C
#define HIDN 128
#define OUTC 32

// ---------------------------------------------------------------- graph build
__global__ void k_hist(const int* __restrict__ ei, int* cur1, int* cur2) {
  int e = blockIdx.x * 256 + threadIdx.x;
  if (e < EE) {
    atomicAdd(&cur1[ei[EE + e]], 1);  // conv1 aggregates at dst = row 1
    atomicAdd(&cur2[ei[e]], 1);       // conv2 aggregates at src = row 0
  }
}

__device__ void scan_one(int* cur, int* off, int* part) {
  const int t = threadIdx.x;
  const int CHK = 20;                 // 1024*20 = 20480 >= 20000
  int base = t * CHK;
  int loc[CHK];
  int s = 0;
#pragma unroll
  for (int i = 0; i < CHK; ++i) {
    int idx = base + i;
    int v = (idx < NN) ? cur[idx] : 0;
    loc[i] = s;
    s += v;
  }
  part[t] = s;
  __syncthreads();
  for (int d = 1; d < 1024; d <<= 1) {
    int v2 = (t >= d) ? part[t - d] : 0;
    __syncthreads();
    part[t] += v2;
    __syncthreads();
  }
  int cbase = part[t] - s;  // exclusive base of this chunk
#pragma unroll
  for (int i = 0; i < CHK; ++i) {
    int idx = base + i;
    if (idx < NN) {
      int o = cbase + loc[i];
      off[idx] = o;
      cur[idx] = o;  // scatter cursor
    }
  }
  if (t == 1023) off[NN] = part[1023];
  __syncthreads();
}

__global__ __launch_bounds__(1024) void k_scan(int* cur1, int* off1, int* cur2, int* off2) {
  __shared__ int part[1024];
  scan_one(cur1, off1, part);
  scan_one(cur2, off2, part);
}

__global__ void k_scatter(const int* __restrict__ ei, int* cur1, int* cur2,
                          int* __restrict__ eid1, int* __restrict__ eid2) {
  int e = blockIdx.x * 256 + threadIdx.x;
  if (e < EE) {
    int p1 = atomicAdd(&cur1[ei[EE + e]], 1);
    eid1[p1] = e;
    int p2 = atomicAdd(&cur2[ei[e]], 1);
    eid2[p2] = e;
  }
}

// ---------------------------------------------------------------- fp32 GEMM
// C[M,Nc] = A[M,K] @ W[K,Nc] (+bias) (+elu).  BM=BN=64, BK=32, 256 thr, 4x4/thr.
template <int ACT>
__global__ __launch_bounds__(256) void k_gemm(const float* __restrict__ A,
                                              const float* __restrict__ W,
                                              const float* __restrict__ bias,
                                              float* __restrict__ Cout,
                                              int M, int K, int Nc) {
  __shared__ float As[32][68];  // transposed: As[k][m]
  __shared__ float Bs[32][68];  // Bs[k][n]
  const int t = threadIdx.x;
  const int bm = blockIdx.x, bn = blockIdx.y;
  const int tx = t & 15, ty = t >> 4;
  const int arow = t >> 2;         // 0..63 tile-m
  const int acol = (t & 3) * 8;    // 0..24 tile-k
  const int brow = t >> 3;         // 0..31 tile-k
  const int bcol = (t & 7) * 8;    // 0..56 tile-n
  const int gm = bm * 64 + arow;
  float acc[4][4] = {};

  for (int k0 = 0; k0 < K; k0 += 32) {
    float4 av0 = make_float4(0.f, 0.f, 0.f, 0.f), av1 = av0;
    if (gm < M) {
      const float4* ap = (const float4*)(A + (size_t)gm * K + k0 + acol);
      av0 = ap[0];
      av1 = ap[1];
    }
    float4 bv0 = make_float4(0.f, 0.f, 0.f, 0.f), bv1 = bv0;
    int gcol = bn * 64 + bcol;
    if (gcol < Nc) {
      const float4* bp = (const float4*)(W + (size_t)(k0 + brow) * Nc + gcol);
      bv0 = bp[0];
      bv1 = bp[1];
    }
    __syncthreads();
    As[acol + 0][arow] = av0.x;
    As[acol + 1][arow] = av0.y;
    As[acol + 2][arow] = av0.z;
    As[acol + 3][arow] = av0.w;
    As[acol + 4][arow] = av1.x;
    As[acol + 5][arow] = av1.y;
    As[acol + 6][arow] = av1.z;
    As[acol + 7][arow] = av1.w;
    *(float4*)&Bs[brow][bcol] = bv0;
    *(float4*)&Bs[brow][bcol + 4] = bv1;
    __syncthreads();
#pragma unroll
    for (int kk = 0; kk < 32; ++kk) {
      float4 a4 = *(const float4*)&As[kk][ty * 4];
      float4 b4 = *(const float4*)&Bs[kk][tx * 4];
      float ar[4] = {a4.x, a4.y, a4.z, a4.w};
      float br[4] = {b4.x, b4.y, b4.z, b4.w};
#pragma unroll
      for (int i = 0; i < 4; ++i)
#pragma unroll
        for (int j = 0; j < 4; ++j) acc[i][j] = fmaf(ar[i], br[j], acc[i][j]);
    }
  }
#pragma unroll
  for (int i = 0; i < 4; ++i) {
    int row = bm * 64 + ty * 4 + i;
    if (row >= M) continue;
#pragma unroll
    for (int j = 0; j < 4; ++j) {
      int col = bn * 64 + tx * 4 + j;
      if (col >= Nc) continue;
      float v = acc[i][j];
      if (bias) v += bias[col];
      if (ACT) v = v > 0.f ? v : (expf(v) - 1.f);
      Cout[(size_t)row * Nc + col] = v;
    }
  }
}

// ------------------------------------------------------- attention dot scores
__global__ void k_att(const float* __restrict__ hbuf, const float* __restrict__ asv,
                      const float* __restrict__ adv, float* __restrict__ a_s,
                      float* __restrict__ a_d) {
  int i = blockIdx.x * 256 + threadIdx.x;
  if (i >= NN * HH) return;
  int n = i >> 4, h = i & 15;
  const float* hp = hbuf + (size_t)n * HC + h * CC;
  const float* sv = asv + h * CC;
  const float* dv = adv + h * CC;
  float ss = 0.f, dd = 0.f;
#pragma unroll
  for (int c = 0; c < CC; ++c) {
    float v = hp[c];
    ss += v * sv[c];
    dd += v * dv[c];
  }
  a_s[i] = ss;
  a_d[i] = dd;
}

// ----------------------------------------------- per-node softmax stats (m, 1/den)
// one wave per node; lane = j*16 + h  (h = head, j = 4-way edge parallel)
__global__ __launch_bounds__(256) void k_stats(const int* __restrict__ srow,
                                               const int* __restrict__ off,
                                               const int* __restrict__ eid,
                                               const float* __restrict__ a_s,
                                               const float* __restrict__ a_d,
                                               float* __restrict__ mbuf,
                                               float* __restrict__ invd) {
  int node = blockIdx.x * 4 + (threadIdx.x >> 6);
  if (node >= NN) return;
  int lane = threadIdx.x & 63;
  int h = lane & 15, j = lane >> 4;
  int e0 = off[node], e1 = off[node + 1];
  float adh = a_d[node * HH + h];
  float mx = -INFINITY;
  for (int p = e0 + j; p < e1; p += 4) {
    int s = srow[eid[p]];
    float a = a_s[s * HH + h] + adh;
    a = a > 0.f ? a : 0.2f * a;
    mx = fmaxf(mx, a);
  }
  mx = fmaxf(mx, __shfl_xor(mx, 16));
  mx = fmaxf(mx, __shfl_xor(mx, 32));
  float sum = 0.f;
  for (int p = e0 + j; p < e1; p += 4) {
    int s = srow[eid[p]];
    float a = a_s[s * HH + h] + adh;
    a = a > 0.f ? a : 0.2f * a;
    sum += __expf(a - mx);
  }
  sum += __shfl_xor(sum, 16);
  sum += __shfl_xor(sum, 32);
  if (j == 0) {
    mbuf[node * HH + h] = mx;
    invd[node * HH + h] = 1.f / (sum + 1e-16f);
  }
}

// ------------------------------------------------------------- aggregation
// one wave per node; lane covers channels [8*lane, 8*lane+8) -> head = lane/4
__global__ __launch_bounds__(256) void k_agg(const int* __restrict__ srow,
                                             const int* __restrict__ off,
                                             const int* __restrict__ eid,
                                             const float* __restrict__ a_s,
                                             const float* __restrict__ a_d,
                                             const float* __restrict__ mbuf,
                                             const float* __restrict__ invd,
                                             const float* __restrict__ hbuf,
                                             const float* __restrict__ bias,
                                             float* __restrict__ outp) {
  int node = blockIdx.x * 4 + (threadIdx.x >> 6);
  if (node >= NN) return;
  int lane = threadIdx.x & 63;
  int h = lane >> 2;
  int coff = (lane & 3) * 8;
  int e0 = off[node], e1 = off[node + 1];
  float adh = a_d[node * HH + h];
  float mh = mbuf[node * HH + h];
  float idh = invd[node * HH + h];
  float acc[8] = {0.f, 0.f, 0.f, 0.f, 0.f, 0.f, 0.f, 0.f};
  for (int p = e0; p < e1; ++p) {
    int e = eid[p];
    int s = srow[e];
    float a = a_s[s * HH + h] + adh;
    a = a > 0.f ? a : 0.2f * a;
    float w = __expf(a - mh) * idh;
    const float4* hp = (const float4*)(hbuf + (size_t)s * HC + h * CC + coff);
    float4 v0 = hp[0], v1 = hp[1];
    acc[0] = fmaf(w, v0.x, acc[0]);
    acc[1] = fmaf(w, v0.y, acc[1]);
    acc[2] = fmaf(w, v0.z, acc[2]);
    acc[3] = fmaf(w, v0.w, acc[3]);
    acc[4] = fmaf(w, v1.x, acc[4]);
    acc[5] = fmaf(w, v1.y, acc[5]);
    acc[6] = fmaf(w, v1.z, acc[6]);
    acc[7] = fmaf(w, v1.w, acc[7]);
  }
  // sum over heads: reduce across lanes differing in bits 2..5
#pragma unroll
  for (int mk = 4; mk <= 32; mk <<= 1) {
#pragma unroll
    for (int i = 0; i < 8; ++i) acc[i] += __shfl_xor(acc[i], mk);
  }
  if (lane < 4) {
#pragma unroll
    for (int i = 0; i < 8; ++i) {
      int c = coff + i;  // lane<4 -> coff = lane*8
      float v = acc[i] * (1.f / 16.f) + bias[c];
      v = v > 0.f ? v : (expf(v) - 1.f);
      outp[(size_t)node * OUTC + c] = v;
    }
  }
}

// ---------------------------------------------------------------- launch
extern "C" void kernel_launch(void* const* d_in, const int* in_sizes, int n_in,
                              void* d_out, int out_size, void* d_ws, size_t ws_size,
                              hipStream_t stream) {
  const float* x = (const float*)d_in[0];
  const int* ei = (const int*)d_in[1];
  const float* W1 = (const float*)d_in[2];
  const float* att_src1 = (const float*)d_in[3];
  const float* att_dst1 = (const float*)d_in[4];
  const float* b1 = (const float*)d_in[5];
  const float* W2 = (const float*)d_in[6];
  const float* att_src2 = (const float*)d_in[7];
  const float* att_dst2 = (const float*)d_in[8];
  const float* b2 = (const float*)d_in[9];
  const float* lin1_w = (const float*)d_in[10];
  const float* lin1_b = (const float*)d_in[11];
  const float* lin2_w = (const float*)d_in[12];
  const float* lin2_b = (const float*)d_in[13];
  float* out = (float*)d_out;  // [x_in | x_out | x_self], each N*32

  char* w = (char*)d_ws;
  float* h_buf = (float*)w;      w += (size_t)NN * HC * 4;     // 40.96 MB (reused conv1/conv2)
  float* x1 = (float*)w;         w += (size_t)NN * HIDN * 4;   // 10.24 MB
  float* a_s = (float*)w;        w += (size_t)NN * HH * 4;
  float* a_d = (float*)w;        w += (size_t)NN * HH * 4;
  float* mbuf = (float*)w;       w += (size_t)NN * HH * 4;
  float* invd = (float*)w;       w += (size_t)NN * HH * 4;
  int* off1 = (int*)w;           w += (size_t)(NN + 1) * 4;
  int* off2 = (int*)w;           w += (size_t)(NN + 1) * 4;
  int* cur1 = (int*)w;           w += (size_t)NN * 4;
  int* cur2 = (int*)w;           w += (size_t)NN * 4;
  int* eid1 = (int*)w;           w += (size_t)EE * 4;
  int* eid2 = (int*)w;           w += (size_t)EE * 4;

  const int EB = (EE + 255) / 256;
  const int NB4 = (NN + 3) / 4;  // wave-per-node kernels, 4 waves/block

  // CSR build (both directions)
  hipMemsetAsync(cur1, 0, (size_t)NN * 4, stream);
  hipMemsetAsync(cur2, 0, (size_t)NN * 4, stream);
  k_hist<<<EB, 256, 0, stream>>>(ei, cur1, cur2);
  k_scan<<<1, 1024, 0, stream>>>(cur1, off1, cur2, off2);
  k_scatter<<<EB, 256, 0, stream>>>(ei, cur1, cur2, eid1, eid2);

  // self path: x1 = elu(x@lin1_w + lin1_b); x_self = elu(x1@lin2_w + lin2_b)
  k_gemm<1><<<dim3(313, 2), 256, 0, stream>>>(x, lin1_w, lin1_b, x1, NN, FIN, HIDN);
  k_gemm<1><<<dim3(313, 1), 256, 0, stream>>>(x1, lin2_w, lin2_b, out + (size_t)2 * NN * OUTC,
                                              NN, HIDN, OUTC);

  // conv1: messages from row0, aggregate at row1
  k_gemm<0><<<dim3(313, 8), 256, 0, stream>>>(x, W1, nullptr, h_buf, NN, FIN, HC);
  k_att<<<(NN * HH + 255) / 256, 256, 0, stream>>>(h_buf, att_src1, att_dst1, a_s, a_d);
  k_stats<<<NB4, 256, 0, stream>>>(ei, off1, eid1, a_s, a_d, mbuf, invd);
  k_agg<<<NB4, 256, 0, stream>>>(ei, off1, eid1, a_s, a_d, mbuf, invd, h_buf, b1, out);

  // conv2: messages from row1, aggregate at row0
  k_gemm<0><<<dim3(313, 8), 256, 0, stream>>>(x, W2, nullptr, h_buf, NN, FIN, HC);
  k_att<<<(NN * HH + 255) / 256, 256, 0, stream>>>(h_buf, att_src2, att_dst2, a_s, a_d);
  k_stats<<<NB4, 256, 0, stream>>>(ei + EE, off2, eid2, a_s, a_d, mbuf, invd);
  k_agg<<<NB4, 256, 0, stream>>>(ei + EE, off2, eid2, a_s, a_d, mbuf, invd, h_buf, b2,
                                 out + (size_t)NN * OUTC);
}

// Round 2
// 460.479 us; speedup vs baseline: 1.4582x; 1.4582x over previous
//
#include <hip/hip_runtime.h>
#include <math.h>

#define NN 20000
#define EE 400000
#define FIN 256
#define HH 16
#define CC 32
#define HC 512    // H*C
#define HIDN 128
#define OUTC 32

typedef unsigned short u16;
typedef __attribute__((ext_vector_type(8))) short short8v;
typedef __attribute__((ext_vector_type(4))) float f32x4;

__device__ inline u16 f2bf(float f) {
  unsigned u = __builtin_bit_cast(unsigned, f);
  unsigned r = (u + 0x7fffu + ((u >> 16) & 1u)) >> 16;
  return (u16)r;
}
__device__ inline float bf2f(u16 b) {
  unsigned u = ((unsigned)b) << 16;
  return __builtin_bit_cast(float, u);
}

// ---------------------------------------------------------------- graph build
__global__ void k_hist(const int* __restrict__ ei, int* cur1, int* cur2) {
  int e = blockIdx.x * 256 + threadIdx.x;
  if (e < EE) {
    atomicAdd(&cur1[ei[EE + e]], 1);  // conv1 aggregates at dst = row 1
    atomicAdd(&cur2[ei[e]], 1);       // conv2 aggregates at src = row 0
  }
}

__device__ void scan_one(int* cur, int* off, int* part) {
  const int t = threadIdx.x;
  const int CHK = 20;                 // 1024*20 = 20480 >= 20000
  int base = t * CHK;
  int loc[CHK];
  int s = 0;
#pragma unroll
  for (int i = 0; i < CHK; ++i) {
    int idx = base + i;
    int v = (idx < NN) ? cur[idx] : 0;
    loc[i] = s;
    s += v;
  }
  part[t] = s;
  __syncthreads();
  for (int d = 1; d < 1024; d <<= 1) {
    int v2 = (t >= d) ? part[t - d] : 0;
    __syncthreads();
    part[t] += v2;
    __syncthreads();
  }
  int cbase = part[t] - s;  // exclusive base of this chunk
#pragma unroll
  for (int i = 0; i < CHK; ++i) {
    int idx = base + i;
    if (idx < NN) {
      int o = cbase + loc[i];
      off[idx] = o;
      cur[idx] = o;  // scatter cursor
    }
  }
  if (t == 1023) off[NN] = part[1023];
  __syncthreads();
}

__global__ __launch_bounds__(1024) void k_scan(int* cur1, int* off1, int* cur2, int* off2) {
  __shared__ int part[1024];
  scan_one(cur1, off1, part);
  scan_one(cur2, off2, part);
}

__global__ void k_scatter(const int* __restrict__ ei, int* cur1, int* cur2,
                          int* __restrict__ eid1, int* __restrict__ eid2) {
  int e = blockIdx.x * 256 + threadIdx.x;
  if (e < EE) {
    int p1 = atomicAdd(&cur1[ei[EE + e]], 1);
    eid1[p1] = e;
    int p2 = atomicAdd(&cur2[ei[e]], 1);
    eid2[p2] = e;
  }
}

// ---------------------------------------------------------------- converts
__global__ void k_x2bf(const float* __restrict__ X, u16* __restrict__ Xb, int n8) {
  int i = blockIdx.x * 256 + threadIdx.x;
  if (i >= n8) return;
  float4 v0 = ((const float4*)X)[i * 2];
  float4 v1 = ((const float4*)X)[i * 2 + 1];
  short8v o;
  o[0] = (short)f2bf(v0.x); o[1] = (short)f2bf(v0.y);
  o[2] = (short)f2bf(v0.z); o[3] = (short)f2bf(v0.w);
  o[4] = (short)f2bf(v1.x); o[5] = (short)f2bf(v1.y);
  o[6] = (short)f2bf(v1.z); o[7] = (short)f2bf(v1.w);
  *(short8v*)(Xb + (size_t)i * 8) = o;
}

// Wt[n][k] = bf16(W[k][n])
__global__ void k_wt(const float* __restrict__ W, u16* __restrict__ Wt, int K, int Nc) {
  int i = blockIdx.x * 256 + threadIdx.x;
  if (i >= K * Nc) return;
  int n = i / K, k = i % K;
  Wt[i] = f2bf(W[(size_t)k * Nc + n]);
}

// ---------------------------------------------------------------- bf16 MFMA GEMM
// C[M,Nc] = A[M,K](bf16) @ Bt[Nc,K](bf16)^T.  Tile 128x128, BK=32, 4 waves 2x2,
// each wave 64x64 = 4x4 fragments of 16x16x32.
template <int ACT, int OUT_BF16>
__global__ __launch_bounds__(256) void k_mfma_gemm(const u16* __restrict__ A,
                                                   const u16* __restrict__ Bt,
                                                   const float* __restrict__ bias,
                                                   void* __restrict__ Cout,
                                                   int M, int K, int Nc) {
  __shared__ u16 As[128 * 40];  // row stride 40 bf16 (80B) -> balanced banks
  __shared__ u16 Bs[128 * 40];
  const int t = threadIdx.x;
  const int lane = t & 63, wave = t >> 6;
  const int wr = (wave >> 1) * 64, wc = (wave & 1) * 64;
  const int bm = blockIdx.x * 128, bn = blockIdx.y * 128;
  const int l15 = lane & 15, l4 = lane >> 4;
  // staging: 4 threads per row, 8 bf16 (16B) each; rows t>>2 and 64+(t>>2)
  const int srow = t >> 2, skoff = (t & 3) * 8;
  int aR0 = bm + srow;        if (aR0 >= M) aR0 = M - 1;
  int aR1 = bm + 64 + srow;   if (aR1 >= M) aR1 = M - 1;
  const int bR0 = bn + srow, bR1 = bn + 64 + srow;  // Nc % 128 == 0

  f32x4 acc[4][4] = {};

  for (int k0 = 0; k0 < K; k0 += 32) {
    short8v a0 = *(const short8v*)(A + (size_t)aR0 * K + k0 + skoff);
    short8v a1 = *(const short8v*)(A + (size_t)aR1 * K + k0 + skoff);
    short8v b0 = *(const short8v*)(Bt + (size_t)bR0 * K + k0 + skoff);
    short8v b1 = *(const short8v*)(Bt + (size_t)bR1 * K + k0 + skoff);
    __syncthreads();
    *(short8v*)(As + srow * 40 + skoff) = a0;
    *(short8v*)(As + (64 + srow) * 40 + skoff) = a1;
    *(short8v*)(Bs + srow * 40 + skoff) = b0;
    *(short8v*)(Bs + (64 + srow) * 40 + skoff) = b1;
    __syncthreads();
    short8v af[4], bfr[4];
#pragma unroll
    for (int i = 0; i < 4; ++i)
      af[i] = *(const short8v*)(As + (wr + i * 16 + l15) * 40 + l4 * 8);
#pragma unroll
    for (int j = 0; j < 4; ++j)
      bfr[j] = *(const short8v*)(Bs + (wc + j * 16 + l15) * 40 + l4 * 8);
#pragma unroll
    for (int i = 0; i < 4; ++i)
#pragma unroll
      for (int j = 0; j < 4; ++j)
        acc[i][j] = __builtin_amdgcn_mfma_f32_16x16x32_bf16(af[i], bfr[j], acc[i][j], 0, 0, 0);
  }

#pragma unroll
  for (int i = 0; i < 4; ++i)
#pragma unroll
    for (int j = 0; j < 4; ++j)
#pragma unroll
      for (int r = 0; r < 4; ++r) {
        int row = bm + wr + i * 16 + l4 * 4 + r;
        int col = bn + wc + j * 16 + l15;
        if (row < M) {
          float v = acc[i][j][r];
          if (ACT == 1) {
            v += bias[col];
            v = v > 0.f ? v : (expf(v) - 1.f);
          }
          if (OUT_BF16)
            ((u16*)Cout)[(size_t)row * Nc + col] = f2bf(v);
          else
            ((float*)Cout)[(size_t)row * Nc + col] = v;
        }
      }
}

// ---------------------------------------------------------------- fp32 GEMM (lin2)
template <int ACT>
__global__ __launch_bounds__(256) void k_gemm(const float* __restrict__ A,
                                              const float* __restrict__ W,
                                              const float* __restrict__ bias,
                                              float* __restrict__ Cout,
                                              int M, int K, int Nc) {
  __shared__ float As[32][68];
  __shared__ float Bs[32][68];
  const int t = threadIdx.x;
  const int bm = blockIdx.x, bn = blockIdx.y;
  const int tx = t & 15, ty = t >> 4;
  const int arow = t >> 2;
  const int acol = (t & 3) * 8;
  const int brow = t >> 3;
  const int bcol = (t & 7) * 8;
  const int gm = bm * 64 + arow;
  float acc[4][4] = {};

  for (int k0 = 0; k0 < K; k0 += 32) {
    float4 av0 = make_float4(0.f, 0.f, 0.f, 0.f), av1 = av0;
    if (gm < M) {
      const float4* ap = (const float4*)(A + (size_t)gm * K + k0 + acol);
      av0 = ap[0];
      av1 = ap[1];
    }
    float4 bv0 = make_float4(0.f, 0.f, 0.f, 0.f), bv1 = bv0;
    int gcol = bn * 64 + bcol;
    if (gcol < Nc) {
      const float4* bp = (const float4*)(W + (size_t)(k0 + brow) * Nc + gcol);
      bv0 = bp[0];
      bv1 = bp[1];
    }
    __syncthreads();
    As[acol + 0][arow] = av0.x;
    As[acol + 1][arow] = av0.y;
    As[acol + 2][arow] = av0.z;
    As[acol + 3][arow] = av0.w;
    As[acol + 4][arow] = av1.x;
    As[acol + 5][arow] = av1.y;
    As[acol + 6][arow] = av1.z;
    As[acol + 7][arow] = av1.w;
    *(float4*)&Bs[brow][bcol] = bv0;
    *(float4*)&Bs[brow][bcol + 4] = bv1;
    __syncthreads();
#pragma unroll
    for (int kk = 0; kk < 32; ++kk) {
      float4 a4 = *(const float4*)&As[kk][ty * 4];
      float4 b4 = *(const float4*)&Bs[kk][tx * 4];
      float ar[4] = {a4.x, a4.y, a4.z, a4.w};
      float br[4] = {b4.x, b4.y, b4.z, b4.w};
#pragma unroll
      for (int i = 0; i < 4; ++i)
#pragma unroll
        for (int j = 0; j < 4; ++j) acc[i][j] = fmaf(ar[i], br[j], acc[i][j]);
    }
  }
#pragma unroll
  for (int i = 0; i < 4; ++i) {
    int row = bm * 64 + ty * 4 + i;
    if (row >= M) continue;
#pragma unroll
    for (int j = 0; j < 4; ++j) {
      int col = bn * 64 + tx * 4 + j;
      if (col >= Nc) continue;
      float v = acc[i][j];
      if (bias) v += bias[col];
      if (ACT) v = v > 0.f ? v : (expf(v) - 1.f);
      Cout[(size_t)row * Nc + col] = v;
    }
  }
}

// ------------------------------------------------------- attention dot scores
__global__ void k_att(const u16* __restrict__ hbuf, const float* __restrict__ asv,
                      const float* __restrict__ adv, float* __restrict__ a_s,
                      float* __restrict__ a_d) {
  int i = blockIdx.x * 256 + threadIdx.x;
  if (i >= NN * HH) return;
  int n = i >> 4, h = i & 15;
  const u16* hp = hbuf + (size_t)n * HC + h * CC;
  const float* sv = asv + h * CC;
  const float* dv = adv + h * CC;
  float ss = 0.f, dd = 0.f;
#pragma unroll
  for (int q = 0; q < 4; ++q) {
    short8v hv = *(const short8v*)(hp + q * 8);
#pragma unroll
    for (int j = 0; j < 8; ++j) {
      float v = bf2f((u16)hv[j]);
      int c = q * 8 + j;
      ss += v * sv[c];
      dd += v * dv[c];
    }
  }
  a_s[i] = ss;
  a_d[i] = dd;
}

// ----------------------------------------------- per-node softmax stats (m, 1/den)
__global__ __launch_bounds__(256) void k_stats(const int* __restrict__ srow,
                                               const int* __restrict__ off,
                                               const int* __restrict__ eid,
                                               const float* __restrict__ a_s,
                                               const float* __restrict__ a_d,
                                               float* __restrict__ mbuf,
                                               float* __restrict__ invd) {
  int node = blockIdx.x * 4 + (threadIdx.x >> 6);
  if (node >= NN) return;
  int lane = threadIdx.x & 63;
  int h = lane & 15, j = lane >> 4;
  int e0 = off[node], e1 = off[node + 1];
  float adh = a_d[node * HH + h];
  float mx = -INFINITY;
  for (int p = e0 + j; p < e1; p += 4) {
    int s = srow[eid[p]];
    float a = a_s[s * HH + h] + adh;
    a = a > 0.f ? a : 0.2f * a;
    mx = fmaxf(mx, a);
  }
  mx = fmaxf(mx, __shfl_xor(mx, 16));
  mx = fmaxf(mx, __shfl_xor(mx, 32));
  float sum = 0.f;
  for (int p = e0 + j; p < e1; p += 4) {
    int s = srow[eid[p]];
    float a = a_s[s * HH + h] + adh;
    a = a > 0.f ? a : 0.2f * a;
    sum += __expf(a - mx);
  }
  sum += __shfl_xor(sum, 16);
  sum += __shfl_xor(sum, 32);
  if (j == 0) {
    mbuf[node * HH + h] = mx;
    invd[node * HH + h] = 1.f / (sum + 1e-16f);
  }
}

// ------------------------------------------------------------- aggregation (bf16 h)
__global__ __launch_bounds__(256) void k_agg(const int* __restrict__ srow,
                                             const int* __restrict__ off,
                                             const int* __restrict__ eid,
                                             const float* __restrict__ a_s,
                                             const float* __restrict__ a_d,
                                             const float* __restrict__ mbuf,
                                             const float* __restrict__ invd,
                                             const u16* __restrict__ hbuf,
                                             const float* __restrict__ bias,
                                             float* __restrict__ outp) {
  int node = blockIdx.x * 4 + (threadIdx.x >> 6);
  if (node >= NN) return;
  int lane = threadIdx.x & 63;
  int h = lane >> 2;
  int coff = (lane & 3) * 8;
  int e0 = off[node], e1 = off[node + 1];
  float adh = a_d[node * HH + h];
  float mh = mbuf[node * HH + h];
  float idh = invd[node * HH + h];
  float acc[8] = {0.f, 0.f, 0.f, 0.f, 0.f, 0.f, 0.f, 0.f};
  for (int p = e0; p < e1; ++p) {
    int e = eid[p];
    int s = srow[e];
    float a = a_s[s * HH + h] + adh;
    a = a > 0.f ? a : 0.2f * a;
    float w = __expf(a - mh) * idh;
    short8v hv = *(const short8v*)(hbuf + (size_t)s * HC + h * CC + coff);
#pragma unroll
    for (int i = 0; i < 8; ++i) acc[i] = fmaf(w, bf2f((u16)hv[i]), acc[i]);
  }
#pragma unroll
  for (int mk = 4; mk <= 32; mk <<= 1) {
#pragma unroll
    for (int i = 0; i < 8; ++i) acc[i] += __shfl_xor(acc[i], mk);
  }
  if (lane < 4) {
#pragma unroll
    for (int i = 0; i < 8; ++i) {
      int c = coff + i;
      float v = acc[i] * (1.f / 16.f) + bias[c];
      v = v > 0.f ? v : (expf(v) - 1.f);
      outp[(size_t)node * OUTC + c] = v;
    }
  }
}

// ---------------------------------------------------------------- launch
extern "C" void kernel_launch(void* const* d_in, const int* in_sizes, int n_in,
                              void* d_out, int out_size, void* d_ws, size_t ws_size,
                              hipStream_t stream) {
  const float* x = (const float*)d_in[0];
  const int* ei = (const int*)d_in[1];
  const float* W1 = (const float*)d_in[2];
  const float* att_src1 = (const float*)d_in[3];
  const float* att_dst1 = (const float*)d_in[4];
  const float* b1 = (const float*)d_in[5];
  const float* W2 = (const float*)d_in[6];
  const float* att_src2 = (const float*)d_in[7];
  const float* att_dst2 = (const float*)d_in[8];
  const float* b2 = (const float*)d_in[9];
  const float* lin1_w = (const float*)d_in[10];
  const float* lin1_b = (const float*)d_in[11];
  const float* lin2_w = (const float*)d_in[12];
  const float* lin2_b = (const float*)d_in[13];
  float* out = (float*)d_out;  // [x_in | x_out | x_self], each N*32

  char* w = (char*)d_ws;
  u16* h_buf = (u16*)w;     w += (size_t)NN * HC * 2;      // 20.48 MB bf16
  u16* x_bf = (u16*)w;      w += (size_t)NN * FIN * 2;     // 10.24 MB bf16
  u16* wt1 = (u16*)w;       w += (size_t)HC * FIN * 2;     // 512x256 bf16
  u16* wt2 = (u16*)w;       w += (size_t)HC * FIN * 2;
  u16* lt1 = (u16*)w;       w += (size_t)HIDN * FIN * 2;   // 128x256 bf16
  float* x1 = (float*)w;    w += (size_t)NN * HIDN * 4;    // 10.24 MB
  float* a_s = (float*)w;   w += (size_t)NN * HH * 4;
  float* a_d = (float*)w;   w += (size_t)NN * HH * 4;
  float* mbuf = (float*)w;  w += (size_t)NN * HH * 4;
  float* invd = (float*)w;  w += (size_t)NN * HH * 4;
  int* off1 = (int*)w;      w += (size_t)(NN + 1) * 4;
  int* off2 = (int*)w;      w += (size_t)(NN + 1) * 4;
  int* cur1 = (int*)w;      w += (size_t)NN * 4;
  int* cur2 = (int*)w;      w += (size_t)NN * 4;
  int* eid1 = (int*)w;      w += (size_t)EE * 4;
  int* eid2 = (int*)w;      w += (size_t)EE * 4;

  const int EB = (EE + 255) / 256;
  const int NB4 = (NN + 3) / 4;
  const int MB = (NN + 127) / 128;  // 157

  // CSR build (both directions)
  hipMemsetAsync(cur1, 0, (size_t)NN * 4, stream);
  hipMemsetAsync(cur2, 0, (size_t)NN * 4, stream);
  k_hist<<<EB, 256, 0, stream>>>(ei, cur1, cur2);
  k_scan<<<1, 1024, 0, stream>>>(cur1, off1, cur2, off2);
  k_scatter<<<EB, 256, 0, stream>>>(ei, cur1, cur2, eid1, eid2);

  // converts
  k_x2bf<<<(NN * FIN / 8 + 255) / 256, 256, 0, stream>>>(x, x_bf, NN * FIN / 8);
  k_wt<<<(FIN * HC + 255) / 256, 256, 0, stream>>>(W1, wt1, FIN, HC);
  k_wt<<<(FIN * HC + 255) / 256, 256, 0, stream>>>(W2, wt2, FIN, HC);
  k_wt<<<(FIN * HIDN + 255) / 256, 256, 0, stream>>>(lin1_w, lt1, FIN, HIDN);

  // self path: x1 = elu(x@lin1 + b) [MFMA, fp32 out]; x_self = elu(x1@lin2 + b) [fp32]
  k_mfma_gemm<1, 0><<<dim3(MB, 1), 256, 0, stream>>>(x_bf, lt1, lin1_b, x1, NN, FIN, HIDN);
  k_gemm<1><<<dim3(313, 1), 256, 0, stream>>>(x1, lin2_w, lin2_b, out + (size_t)2 * NN * OUTC,
                                              NN, HIDN, OUTC);

  // conv1: messages from row0, aggregate at row1
  k_mfma_gemm<0, 1><<<dim3(MB, 4), 256, 0, stream>>>(x_bf, wt1, nullptr, h_buf, NN, FIN, HC);
  k_att<<<(NN * HH + 255) / 256, 256, 0, stream>>>(h_buf, att_src1, att_dst1, a_s, a_d);
  k_stats<<<NB4, 256, 0, stream>>>(ei, off1, eid1, a_s, a_d, mbuf, invd);
  k_agg<<<NB4, 256, 0, stream>>>(ei, off1, eid1, a_s, a_d, mbuf, invd, h_buf, b1, out);

  // conv2: messages from row1, aggregate at row0
  k_mfma_gemm<0, 1><<<dim3(MB, 4), 256, 0, stream>>>(x_bf, wt2, nullptr, h_buf, NN, FIN, HC);
  k_att<<<(NN * HH + 255) / 256, 256, 0, stream>>>(h_buf, att_src2, att_dst2, a_s, a_d);
  k_stats<<<NB4, 256, 0, stream>>>(ei + EE, off2, eid2, a_s, a_d, mbuf, invd);
  k_agg<<<NB4, 256, 0, stream>>>(ei + EE, off2, eid2, a_s, a_d, mbuf, invd, h_buf, b2,
                                 out + (size_t)NN * OUTC);
}

// Round 3
// 393.962 us; speedup vs baseline: 1.7045x; 1.1688x over previous
//
#include <hip/hip_runtime.h>
#include <math.h>

#define NN 20000
#define EE 400000
#define FIN 256
#define HH 16
#define CC 32
#define HC 512    // H*C
#define HIDN 128
#define OUTC 32

typedef unsigned short u16;
typedef __attribute__((ext_vector_type(8))) short short8v;
typedef __attribute__((ext_vector_type(4))) float f32x4;

__device__ inline u16 f2bf(float f) {
  unsigned u = __builtin_bit_cast(unsigned, f);
  unsigned r = (u + 0x7fffu + ((u >> 16) & 1u)) >> 16;
  return (u16)r;
}
__device__ inline float bf2f(u16 b) {
  unsigned u = ((unsigned)b) << 16;
  return __builtin_bit_cast(float, u);
}

// ---------------------------------------------------------------- graph build
__global__ void k_hist(const int* __restrict__ ei, int* cur1, int* cur2) {
  int e = blockIdx.x * 256 + threadIdx.x;
  if (e < EE) {
    atomicAdd(&cur1[ei[EE + e]], 1);  // conv1 aggregates at dst = row 1
    atomicAdd(&cur2[ei[e]], 1);       // conv2 aggregates at src = row 0
  }
}

__device__ void scan_one(int* cur, int* off, int* part) {
  const int t = threadIdx.x;
  const int CHK = 20;
  int base = t * CHK;
  int loc[CHK];
  int s = 0;
#pragma unroll
  for (int i = 0; i < CHK; ++i) {
    int idx = base + i;
    int v = (idx < NN) ? cur[idx] : 0;
    loc[i] = s;
    s += v;
  }
  part[t] = s;
  __syncthreads();
  for (int d = 1; d < 1024; d <<= 1) {
    int v2 = (t >= d) ? part[t - d] : 0;
    __syncthreads();
    part[t] += v2;
    __syncthreads();
  }
  int cbase = part[t] - s;
#pragma unroll
  for (int i = 0; i < CHK; ++i) {
    int idx = base + i;
    if (idx < NN) {
      int o = cbase + loc[i];
      off[idx] = o;
      cur[idx] = o;
    }
  }
  if (t == 1023) off[NN] = part[1023];
  __syncthreads();
}

__global__ __launch_bounds__(1024) void k_scan(int* cur1, int* off1, int* cur2, int* off2) {
  __shared__ int part[1024];
  scan_one(cur1, off1, part);
  scan_one(cur2, off2, part);
}

// writes adj (source node in CSR order) directly
__global__ void k_scatter(const int* __restrict__ ei, int* cur1, int* cur2,
                          int* __restrict__ adj1, int* __restrict__ adj2) {
  int e = blockIdx.x * 256 + threadIdx.x;
  if (e < EE) {
    int s1 = ei[e], d1 = ei[EE + e];
    int p1 = atomicAdd(&cur1[d1], 1);
    adj1[p1] = s1;                      // conv1: message source = row0
    int p2 = atomicAdd(&cur2[s1], 1);
    adj2[p2] = d1;                      // conv2: message source = row1
  }
}

// ---------------------------------------------------------------- converts
__global__ void k_x2bf(const float* __restrict__ X, u16* __restrict__ Xb, int n8) {
  int i = blockIdx.x * 256 + threadIdx.x;
  if (i >= n8) return;
  float4 v0 = ((const float4*)X)[i * 2];
  float4 v1 = ((const float4*)X)[i * 2 + 1];
  short8v o;
  o[0] = (short)f2bf(v0.x); o[1] = (short)f2bf(v0.y);
  o[2] = (short)f2bf(v0.z); o[3] = (short)f2bf(v0.w);
  o[4] = (short)f2bf(v1.x); o[5] = (short)f2bf(v1.y);
  o[6] = (short)f2bf(v1.z); o[7] = (short)f2bf(v1.w);
  *(short8v*)(Xb + (size_t)i * 8) = o;
}

// Wt[n][k] = bf16(W[k][n])
__global__ void k_wt(const float* __restrict__ W, u16* __restrict__ Wt, int K, int Nc) {
  int i = blockIdx.x * 256 + threadIdx.x;
  if (i >= K * Nc) return;
  int n = i / K, k = i % K;
  Wt[i] = f2bf(W[(size_t)k * Nc + n]);
}

// ---------------------------------------------------------------- bf16 MFMA GEMM
// C[M,Nc] = A[M,K](bf16) @ Bt[Nc,K]^T.  128x128 tile, BK=32, 4 waves 2x2 of 64x64.
template <int ACT, int OUT_BF16>
__global__ __launch_bounds__(256) void k_mfma_gemm(const u16* __restrict__ A,
                                                   const u16* __restrict__ Bt,
                                                   const float* __restrict__ bias,
                                                   void* __restrict__ Cout,
                                                   int M, int K, int Nc) {
  __shared__ u16 As[128 * 40];
  __shared__ u16 Bs[128 * 40];
  const int t = threadIdx.x;
  const int lane = t & 63, wave = t >> 6;
  const int wr = (wave >> 1) * 64, wc = (wave & 1) * 64;
  const int bm = blockIdx.x * 128, bn = blockIdx.y * 128;
  const int l15 = lane & 15, l4 = lane >> 4;
  const int srow = t >> 2, skoff = (t & 3) * 8;
  int aR0 = bm + srow;        if (aR0 >= M) aR0 = M - 1;
  int aR1 = bm + 64 + srow;   if (aR1 >= M) aR1 = M - 1;
  const int bR0 = bn + srow, bR1 = bn + 64 + srow;

  f32x4 acc[4][4] = {};

  for (int k0 = 0; k0 < K; k0 += 32) {
    short8v a0 = *(const short8v*)(A + (size_t)aR0 * K + k0 + skoff);
    short8v a1 = *(const short8v*)(A + (size_t)aR1 * K + k0 + skoff);
    short8v b0 = *(const short8v*)(Bt + (size_t)bR0 * K + k0 + skoff);
    short8v b1 = *(const short8v*)(Bt + (size_t)bR1 * K + k0 + skoff);
    __syncthreads();
    *(short8v*)(As + srow * 40 + skoff) = a0;
    *(short8v*)(As + (64 + srow) * 40 + skoff) = a1;
    *(short8v*)(Bs + srow * 40 + skoff) = b0;
    *(short8v*)(Bs + (64 + srow) * 40 + skoff) = b1;
    __syncthreads();
    short8v af[4], bfr[4];
#pragma unroll
    for (int i = 0; i < 4; ++i)
      af[i] = *(const short8v*)(As + (wr + i * 16 + l15) * 40 + l4 * 8);
#pragma unroll
    for (int j = 0; j < 4; ++j)
      bfr[j] = *(const short8v*)(Bs + (wc + j * 16 + l15) * 40 + l4 * 8);
#pragma unroll
    for (int i = 0; i < 4; ++i)
#pragma unroll
      for (int j = 0; j < 4; ++j)
        acc[i][j] = __builtin_amdgcn_mfma_f32_16x16x32_bf16(af[i], bfr[j], acc[i][j], 0, 0, 0);
  }

#pragma unroll
  for (int i = 0; i < 4; ++i)
#pragma unroll
    for (int j = 0; j < 4; ++j)
#pragma unroll
      for (int r = 0; r < 4; ++r) {
        int row = bm + wr + i * 16 + l4 * 4 + r;
        int col = bn + wc + j * 16 + l15;
        if (row < M) {
          float v = acc[i][j][r];
          if (ACT == 1) {
            v += bias[col];
            v = v > 0.f ? v : (expf(v) - 1.f);
          }
          if (OUT_BF16)
            ((u16*)Cout)[(size_t)row * Nc + col] = f2bf(v);
          else
            ((float*)Cout)[(size_t)row * Nc + col] = v;
        }
      }
}

// MFMA GEMM for Nc=32, K=128 (lin2): 128x32 tile, 4 waves each 32 rows.
__global__ __launch_bounds__(256) void k_mfma_n32(const u16* __restrict__ A,
                                                  const u16* __restrict__ Bt,
                                                  const float* __restrict__ bias,
                                                  float* __restrict__ Cout, int M) {
  __shared__ u16 As[128 * 40];
  __shared__ u16 Bs[32 * 40];
  const int t = threadIdx.x;
  const int lane = t & 63, wv = t >> 6;
  const int bm = blockIdx.x * 128;
  const int l15 = lane & 15, l4 = lane >> 4;
  const int srow = t >> 2, skoff = (t & 3) * 8;
  int aR0 = bm + srow;        if (aR0 >= M) aR0 = M - 1;
  int aR1 = bm + 64 + srow;   if (aR1 >= M) aR1 = M - 1;

  f32x4 acc[2][2] = {};

  for (int k0 = 0; k0 < 128; k0 += 32) {
    short8v a0 = *(const short8v*)(A + (size_t)aR0 * 128 + k0 + skoff);
    short8v a1 = *(const short8v*)(A + (size_t)aR1 * 128 + k0 + skoff);
    short8v b0 = {};
    if (t < 128) b0 = *(const short8v*)(Bt + (size_t)(t >> 2) * 128 + k0 + skoff);
    __syncthreads();
    *(short8v*)(As + srow * 40 + skoff) = a0;
    *(short8v*)(As + (64 + srow) * 40 + skoff) = a1;
    if (t < 128) *(short8v*)(Bs + (t >> 2) * 40 + skoff) = b0;
    __syncthreads();
    short8v af[2], bfr[2];
#pragma unroll
    for (int i = 0; i < 2; ++i)
      af[i] = *(const short8v*)(As + (wv * 32 + i * 16 + l15) * 40 + l4 * 8);
#pragma unroll
    for (int j = 0; j < 2; ++j)
      bfr[j] = *(const short8v*)(Bs + (j * 16 + l15) * 40 + l4 * 8);
#pragma unroll
    for (int i = 0; i < 2; ++i)
#pragma unroll
      for (int j = 0; j < 2; ++j)
        acc[i][j] = __builtin_amdgcn_mfma_f32_16x16x32_bf16(af[i], bfr[j], acc[i][j], 0, 0, 0);
  }
#pragma unroll
  for (int i = 0; i < 2; ++i)
#pragma unroll
    for (int j = 0; j < 2; ++j)
#pragma unroll
      for (int r = 0; r < 4; ++r) {
        int row = bm + wv * 32 + i * 16 + l4 * 4 + r;
        int col = j * 16 + l15;
        if (row < M) {
          float v = acc[i][j][r] + bias[col];
          v = v > 0.f ? v : (expf(v) - 1.f);
          Cout[(size_t)row * OUTC + col] = v;
        }
      }
}

// ------------------------------------------------------- attention dot scores
__global__ void k_att(const u16* __restrict__ hbuf, const float* __restrict__ asv,
                      const float* __restrict__ adv, float* __restrict__ a_s,
                      float* __restrict__ a_d) {
  int i = blockIdx.x * 256 + threadIdx.x;
  if (i >= NN * HH) return;
  int n = i >> 4, h = i & 15;
  const u16* hp = hbuf + (size_t)n * HC + h * CC;
  const float* sv = asv + h * CC;
  const float* dv = adv + h * CC;
  float ss = 0.f, dd = 0.f;
#pragma unroll
  for (int q = 0; q < 4; ++q) {
    short8v hv = *(const short8v*)(hp + q * 8);
#pragma unroll
    for (int j = 0; j < 8; ++j) {
      float v = bf2f((u16)hv[j]);
      int c = q * 8 + j;
      ss += v * sv[c];
      dd += v * dv[c];
    }
  }
  a_s[i] = ss;
  a_d[i] = dd;
}

// ------------------------- per-node softmax: stash alpha, then ex -> wcsr (bf16)
__global__ __launch_bounds__(256) void k_stats(const int* __restrict__ adj,
                                               const int* __restrict__ off,
                                               const float* __restrict__ a_s,
                                               const float* __restrict__ a_d,
                                               u16* __restrict__ wc,
                                               float* __restrict__ invd) {
  int node = blockIdx.x * 4 + (threadIdx.x >> 6);
  if (node >= NN) return;
  int lane = threadIdx.x & 63;
  int h = lane & 15, j = lane >> 4;
  int e0 = off[node], e1 = off[node + 1];
  float adh = a_d[node * HH + h];
  float mx = -INFINITY;
  for (int p = e0 + j; p < e1; p += 4) {
    int s = adj[p];
    float a = a_s[s * HH + h] + adh;
    a = a > 0.f ? a : 0.2f * a;
    wc[(size_t)p * HH + h] = f2bf(a);
    mx = fmaxf(mx, a);
  }
  mx = fmaxf(mx, __shfl_xor(mx, 16));
  mx = fmaxf(mx, __shfl_xor(mx, 32));
  float sum = 0.f;
  for (int p = e0 + j; p < e1; p += 4) {
    float a = bf2f(wc[(size_t)p * HH + h]);
    float e = __expf(a - mx);
    wc[(size_t)p * HH + h] = f2bf(e);
    sum += e;
  }
  sum += __shfl_xor(sum, 16);
  sum += __shfl_xor(sum, 32);
  if (j == 0) invd[node * HH + h] = 1.f / (sum + 1e-16f);
}

// ------------------------------------------------------------- aggregation
// lane: h = lane>>2 (head), coff = (lane&3)*8. 2-edge unroll, dual accumulators.
__global__ __launch_bounds__(256) void k_agg(const int* __restrict__ adj,
                                             const int* __restrict__ off,
                                             const u16* __restrict__ wc,
                                             const float* __restrict__ invd,
                                             const u16* __restrict__ hbuf,
                                             const float* __restrict__ bias,
                                             float* __restrict__ outp) {
  int node = blockIdx.x * 4 + (threadIdx.x >> 6);
  if (node >= NN) return;
  int lane = threadIdx.x & 63;
  int h = lane >> 2;
  int coff = (lane & 3) * 8;
  int e0 = off[node], e1 = off[node + 1];
  float acc0[8] = {}, acc1[8] = {};
  int p = e0;
  for (; p + 2 <= e1; p += 2) {
    int s0 = adj[p], s1 = adj[p + 1];
    float w0 = bf2f(wc[(size_t)p * HH + h]);
    float w1 = bf2f(wc[(size_t)(p + 1) * HH + h]);
    short8v h0 = *(const short8v*)(hbuf + (size_t)s0 * HC + h * CC + coff);
    short8v h1 = *(const short8v*)(hbuf + (size_t)s1 * HC + h * CC + coff);
#pragma unroll
    for (int i = 0; i < 8; ++i) {
      acc0[i] = fmaf(w0, bf2f((u16)h0[i]), acc0[i]);
      acc1[i] = fmaf(w1, bf2f((u16)h1[i]), acc1[i]);
    }
  }
  if (p < e1) {
    int s0 = adj[p];
    float w0 = bf2f(wc[(size_t)p * HH + h]);
    short8v h0 = *(const short8v*)(hbuf + (size_t)s0 * HC + h * CC + coff);
#pragma unroll
    for (int i = 0; i < 8; ++i) acc0[i] = fmaf(w0, bf2f((u16)h0[i]), acc0[i]);
  }
  float idh = invd[node * HH + h];
  float acc[8];
#pragma unroll
  for (int i = 0; i < 8; ++i) acc[i] = (acc0[i] + acc1[i]) * idh;
#pragma unroll
  for (int mk = 4; mk <= 32; mk <<= 1) {
#pragma unroll
    for (int i = 0; i < 8; ++i) acc[i] += __shfl_xor(acc[i], mk);
  }
  if (lane < 4) {
#pragma unroll
    for (int i = 0; i < 8; ++i) {
      int c = coff + i;
      float v = acc[i] * (1.f / 16.f) + bias[c];
      v = v > 0.f ? v : (expf(v) - 1.f);
      outp[(size_t)node * OUTC + c] = v;
    }
  }
}

// ---------------------------------------------------------------- launch
extern "C" void kernel_launch(void* const* d_in, const int* in_sizes, int n_in,
                              void* d_out, int out_size, void* d_ws, size_t ws_size,
                              hipStream_t stream) {
  const float* x = (const float*)d_in[0];
  const int* ei = (const int*)d_in[1];
  const float* W1 = (const float*)d_in[2];
  const float* att_src1 = (const float*)d_in[3];
  const float* att_dst1 = (const float*)d_in[4];
  const float* b1 = (const float*)d_in[5];
  const float* W2 = (const float*)d_in[6];
  const float* att_src2 = (const float*)d_in[7];
  const float* att_dst2 = (const float*)d_in[8];
  const float* b2 = (const float*)d_in[9];
  const float* lin1_w = (const float*)d_in[10];
  const float* lin1_b = (const float*)d_in[11];
  const float* lin2_w = (const float*)d_in[12];
  const float* lin2_b = (const float*)d_in[13];
  float* out = (float*)d_out;  // [x_in | x_out | x_self], each N*32

  char* w = (char*)d_ws;
  u16* h_buf = (u16*)w;     w += (size_t)NN * HC * 2;      // 20.48 MB
  u16* x_bf = (u16*)w;      w += (size_t)NN * FIN * 2;     // 10.24 MB
  u16* x1b = (u16*)w;       w += (size_t)NN * HIDN * 2;    // 5.12 MB
  u16* wcsr = (u16*)w;      w += (size_t)EE * HH * 2;      // 12.8 MB
  u16* wt1 = (u16*)w;       w += (size_t)HC * FIN * 2;
  u16* wt2 = (u16*)w;       w += (size_t)HC * FIN * 2;
  u16* lt1 = (u16*)w;       w += (size_t)HIDN * FIN * 2;
  u16* lt2 = (u16*)w;       w += (size_t)OUTC * HIDN * 2;
  float* a_s = (float*)w;   w += (size_t)NN * HH * 4;
  float* a_d = (float*)w;   w += (size_t)NN * HH * 4;
  float* invd = (float*)w;  w += (size_t)NN * HH * 4;
  int* off1 = (int*)w;      w += (size_t)(NN + 1) * 4;
  int* off2 = (int*)w;      w += (size_t)(NN + 1) * 4;
  int* cur1 = (int*)w;      w += (size_t)NN * 4;
  int* cur2 = (int*)w;      w += (size_t)NN * 4;
  int* adj1 = (int*)w;      w += (size_t)EE * 4;
  int* adj2 = (int*)w;      w += (size_t)EE * 4;

  const int EB = (EE + 255) / 256;
  const int NB4 = (NN + 3) / 4;
  const int MB = (NN + 127) / 128;  // 157

  // CSR build
  hipMemsetAsync(cur1, 0, (size_t)NN * 4, stream);
  hipMemsetAsync(cur2, 0, (size_t)NN * 4, stream);
  k_hist<<<EB, 256, 0, stream>>>(ei, cur1, cur2);
  k_scan<<<1, 1024, 0, stream>>>(cur1, off1, cur2, off2);
  k_scatter<<<EB, 256, 0, stream>>>(ei, cur1, cur2, adj1, adj2);

  // converts
  k_x2bf<<<(NN * FIN / 8 + 255) / 256, 256, 0, stream>>>(x, x_bf, NN * FIN / 8);
  k_wt<<<(FIN * HC + 255) / 256, 256, 0, stream>>>(W1, wt1, FIN, HC);
  k_wt<<<(FIN * HC + 255) / 256, 256, 0, stream>>>(W2, wt2, FIN, HC);
  k_wt<<<(FIN * HIDN + 255) / 256, 256, 0, stream>>>(lin1_w, lt1, FIN, HIDN);
  k_wt<<<(HIDN * OUTC + 255) / 256, 256, 0, stream>>>(lin2_w, lt2, HIDN, OUTC);

  // self path (MFMA): x1b = elu(x@lin1 + b) bf16; x_self = elu(x1b@lin2 + b)
  k_mfma_gemm<1, 1><<<dim3(MB, 1), 256, 0, stream>>>(x_bf, lt1, lin1_b, x1b, NN, FIN, HIDN);
  k_mfma_n32<<<MB, 256, 0, stream>>>(x1b, lt2, lin2_b, out + (size_t)2 * NN * OUTC, NN);

  // conv1: messages from row0, aggregate at row1
  k_mfma_gemm<0, 1><<<dim3(MB, 4), 256, 0, stream>>>(x_bf, wt1, nullptr, h_buf, NN, FIN, HC);
  k_att<<<(NN * HH + 255) / 256, 256, 0, stream>>>(h_buf, att_src1, att_dst1, a_s, a_d);
  k_stats<<<NB4, 256, 0, stream>>>(adj1, off1, a_s, a_d, wcsr, invd);
  k_agg<<<NB4, 256, 0, stream>>>(adj1, off1, wcsr, invd, h_buf, b1, out);

  // conv2: messages from row1, aggregate at row0
  k_mfma_gemm<0, 1><<<dim3(MB, 4), 256, 0, stream>>>(x_bf, wt2, nullptr, h_buf, NN, FIN, HC);
  k_att<<<(NN * HH + 255) / 256, 256, 0, stream>>>(h_buf, att_src2, att_dst2, a_s, a_d);
  k_stats<<<NB4, 256, 0, stream>>>(adj2, off2, a_s, a_d, wcsr, invd);
  k_agg<<<NB4, 256, 0, stream>>>(adj2, off2, wcsr, invd, h_buf, b2,
                                 out + (size_t)NN * OUTC);
}

// Round 4
// 355.863 us; speedup vs baseline: 1.8869x; 1.1071x over previous
//
#include <hip/hip_runtime.h>
#include <math.h>

#define NN 20000
#define EE 400000
#define FIN 256
#define HH 16
#define CC 32
#define HC 512    // H*C
#define HIDN 128
#define OUTC 32
#define CAPD 96   // per-node LDS edge capacity (deg ~ Poisson(20))

typedef unsigned short u16;
typedef __attribute__((ext_vector_type(8))) short short8v;
typedef __attribute__((ext_vector_type(4))) float f32x4;

__device__ inline u16 f2bf(float f) {
  unsigned u = __builtin_bit_cast(unsigned, f);
  unsigned r = (u + 0x7fffu + ((u >> 16) & 1u)) >> 16;
  return (u16)r;
}
__device__ inline float bf2f(u16 b) {
  unsigned u = ((unsigned)b) << 16;
  return __builtin_bit_cast(float, u);
}

// async global->LDS, 16B per lane; LDS dest is wave-uniform base + lane*16
__device__ __forceinline__ void gload16(const u16* g, u16* l) {
  __builtin_amdgcn_global_load_lds(
      (const __attribute__((address_space(1))) unsigned int*)g,
      (__attribute__((address_space(3))) unsigned int*)l, 16, 0, 0);
}

// ---------------------------------------------------------------- graph build
__global__ void k_hist(const int* __restrict__ ei, int* cur1, int* cur2) {
  int e = blockIdx.x * 256 + threadIdx.x;
  if (e < EE) {
    atomicAdd(&cur1[ei[EE + e]], 1);  // conv1 aggregates at dst = row 1
    atomicAdd(&cur2[ei[e]], 1);       // conv2 aggregates at src = row 0
  }
}

__device__ void scan_one(int* cur, int* off, int* part) {
  const int t = threadIdx.x;
  const int CHK = 20;
  int base = t * CHK;
  int loc[CHK];
  int s = 0;
#pragma unroll
  for (int i = 0; i < CHK; ++i) {
    int idx = base + i;
    int v = (idx < NN) ? cur[idx] : 0;
    loc[i] = s;
    s += v;
  }
  part[t] = s;
  __syncthreads();
  for (int d = 1; d < 1024; d <<= 1) {
    int v2 = (t >= d) ? part[t - d] : 0;
    __syncthreads();
    part[t] += v2;
    __syncthreads();
  }
  int cbase = part[t] - s;
#pragma unroll
  for (int i = 0; i < CHK; ++i) {
    int idx = base + i;
    if (idx < NN) {
      int o = cbase + loc[i];
      off[idx] = o;
      cur[idx] = o;
    }
  }
  if (t == 1023) off[NN] = part[1023];
}

__global__ __launch_bounds__(1024) void k_scan(int* cur1, int* off1, int* cur2, int* off2) {
  __shared__ int part[1024];
  if (blockIdx.x == 0) scan_one(cur1, off1, part);
  else                 scan_one(cur2, off2, part);
}

// writes adj (message-source node in CSR order) directly
__global__ void k_scatter(const int* __restrict__ ei, int* cur1, int* cur2,
                          int* __restrict__ adj1, int* __restrict__ adj2) {
  int e = blockIdx.x * 256 + threadIdx.x;
  if (e < EE) {
    int s1 = ei[e], d1 = ei[EE + e];
    int p1 = atomicAdd(&cur1[d1], 1);
    adj1[p1] = s1;                      // conv1: message source = row0
    int p2 = atomicAdd(&cur2[s1], 1);
    adj2[p2] = d1;                      // conv2: message source = row1
  }
}

// ---------------------------------------------------------- merged converts
// blocks [0,2500): x->bf16 ; [2500,3012): W1^T ; [3012,3524): W2^T ;
// [3524,3652): lin1^T ; [3652,3668): lin2^T   (all exact multiples of 256)
__global__ void k_prep(const float* __restrict__ x, u16* __restrict__ xb,
                       const float* __restrict__ W1, u16* __restrict__ wt1,
                       const float* __restrict__ W2, u16* __restrict__ wt2,
                       const float* __restrict__ L1, u16* __restrict__ lt1,
                       const float* __restrict__ L2, u16* __restrict__ lt2) {
  int b = blockIdx.x, t = threadIdx.x;
  if (b < 2500) {
    int i = b * 256 + t;
    float4 v0 = ((const float4*)x)[i * 2];
    float4 v1 = ((const float4*)x)[i * 2 + 1];
    short8v o;
    o[0] = (short)f2bf(v0.x); o[1] = (short)f2bf(v0.y);
    o[2] = (short)f2bf(v0.z); o[3] = (short)f2bf(v0.w);
    o[4] = (short)f2bf(v1.x); o[5] = (short)f2bf(v1.y);
    o[6] = (short)f2bf(v1.z); o[7] = (short)f2bf(v1.w);
    *(short8v*)(xb + (size_t)i * 8) = o;
  } else if (b < 3012) {
    int i = (b - 2500) * 256 + t;   // [Nc=512][K=256]
    int n = i >> 8, k = i & 255;
    wt1[i] = f2bf(W1[k * HC + n]);
  } else if (b < 3524) {
    int i = (b - 3012) * 256 + t;
    int n = i >> 8, k = i & 255;
    wt2[i] = f2bf(W2[k * HC + n]);
  } else if (b < 3652) {
    int i = (b - 3524) * 256 + t;   // [Nc=128][K=256]
    int n = i >> 8, k = i & 255;
    lt1[i] = f2bf(L1[k * HIDN + n]);
  } else {
    int i = (b - 3652) * 256 + t;   // [Nc=32][K=128]
    int n = i >> 7, k = i & 127;
    lt2[i] = f2bf(L2[k * OUTC + n]);
  }
}

// ---------------------------------------------------------------- bf16 MFMA GEMM
// C[M,Nc] = A[M,K]@Bt[Nc,K]^T. 128x128 tile, BK=64, 4 waves 2x2 of 64x64.
// LDS: linear rows of 64 u16 (128B), slot-swizzled: chunk(row,slot) holds
// global k-chunk kc = slot ^ (row&7). Staged via global_load_lds w=16 with
// pre-swizzled per-lane global source (rule #21: same involution both sides).
template <int ACT, int OUT_BF16>
__global__ __launch_bounds__(256) void k_mfma_gemm(const u16* __restrict__ A,
                                                   const u16* __restrict__ Bt,
                                                   const float* __restrict__ bias,
                                                   void* __restrict__ Cout,
                                                   int M, int K, int Nc) {
  __shared__ u16 As[128 * 64];
  __shared__ u16 Bs[128 * 64];
  const int t = threadIdx.x;
  const int lane = t & 63, wave = t >> 6;
  const int wr = (wave >> 1) * 64, wc = (wave & 1) * 64;
  const int bm = blockIdx.x * 128, bn = blockIdx.y * 128;
  const int l15 = lane & 15, l4 = lane >> 4;
  const int rloc = lane >> 3;                 // 0..7 row-in-group
  const int kc_src = (lane & 7) ^ rloc;       // pre-swizzled source k-chunk

  f32x4 acc[4][4] = {};

  for (int k0 = 0; k0 < K; k0 += 64) {
    __syncthreads();  // all waves done reading LDS from previous iter
#pragma unroll
    for (int q = 0; q < 4; ++q) {
      const int rblk = q * 4 + wave;          // 0..15 (8-row group)
      const int r = rblk * 8 + rloc;          // tile row 0..127
      gload16(A + (size_t)(bm + r) * K + k0 + kc_src * 8, As + rblk * 512);
      gload16(Bt + (size_t)(bn + r) * K + k0 + kc_src * 8, Bs + rblk * 512);
    }
    __syncthreads();  // compiler emits vmcnt(0) drain before barrier
#pragma unroll
    for (int kh = 0; kh < 2; ++kh) {
      const int kc = kh * 4 + l4;
      short8v af[4], bfr[4];
#pragma unroll
      for (int i = 0; i < 4; ++i) {
        int row = wr + i * 16 + l15;
        af[i] = *(const short8v*)(As + row * 64 + (kc ^ (row & 7)) * 8);
      }
#pragma unroll
      for (int j = 0; j < 4; ++j) {
        int row = wc + j * 16 + l15;
        bfr[j] = *(const short8v*)(Bs + row * 64 + (kc ^ (row & 7)) * 8);
      }
#pragma unroll
      for (int i = 0; i < 4; ++i)
#pragma unroll
        for (int j = 0; j < 4; ++j)
          acc[i][j] = __builtin_amdgcn_mfma_f32_16x16x32_bf16(af[i], bfr[j], acc[i][j], 0, 0, 0);
    }
  }

#pragma unroll
  for (int i = 0; i < 4; ++i)
#pragma unroll
    for (int j = 0; j < 4; ++j)
#pragma unroll
      for (int r = 0; r < 4; ++r) {
        int row = bm + wr + i * 16 + l4 * 4 + r;
        int col = bn + wc + j * 16 + l15;
        if (row < M) {
          float v = acc[i][j][r];
          if (ACT == 1) {
            v += bias[col];
            v = v > 0.f ? v : (expf(v) - 1.f);
          }
          if (OUT_BF16)
            ((u16*)Cout)[(size_t)row * Nc + col] = f2bf(v);
          else
            ((float*)Cout)[(size_t)row * Nc + col] = v;
        }
      }
}

// MFMA GEMM for Nc=32, K=128 (lin2): 128x32 tile, 4 waves each 32 rows.
__global__ __launch_bounds__(256) void k_mfma_n32(const u16* __restrict__ A,
                                                  const u16* __restrict__ Bt,
                                                  const float* __restrict__ bias,
                                                  float* __restrict__ Cout, int M) {
  __shared__ u16 As[128 * 40];
  __shared__ u16 Bs[32 * 40];
  const int t = threadIdx.x;
  const int lane = t & 63, wv = t >> 6;
  const int bm = blockIdx.x * 128;
  const int l15 = lane & 15, l4 = lane >> 4;
  const int srow = t >> 2, skoff = (t & 3) * 8;
  int aR0 = bm + srow;        if (aR0 >= M) aR0 = M - 1;
  int aR1 = bm + 64 + srow;   if (aR1 >= M) aR1 = M - 1;

  f32x4 acc[2][2] = {};

  for (int k0 = 0; k0 < 128; k0 += 32) {
    short8v a0 = *(const short8v*)(A + (size_t)aR0 * 128 + k0 + skoff);
    short8v a1 = *(const short8v*)(A + (size_t)aR1 * 128 + k0 + skoff);
    short8v b0 = {};
    if (t < 128) b0 = *(const short8v*)(Bt + (size_t)(t >> 2) * 128 + k0 + skoff);
    __syncthreads();
    *(short8v*)(As + srow * 40 + skoff) = a0;
    *(short8v*)(As + (64 + srow) * 40 + skoff) = a1;
    if (t < 128) *(short8v*)(Bs + (t >> 2) * 40 + skoff) = b0;
    __syncthreads();
    short8v af[2], bfr[2];
#pragma unroll
    for (int i = 0; i < 2; ++i)
      af[i] = *(const short8v*)(As + (wv * 32 + i * 16 + l15) * 40 + l4 * 8);
#pragma unroll
    for (int j = 0; j < 2; ++j)
      bfr[j] = *(const short8v*)(Bs + (j * 16 + l15) * 40 + l4 * 8);
#pragma unroll
    for (int i = 0; i < 2; ++i)
#pragma unroll
      for (int j = 0; j < 2; ++j)
        acc[i][j] = __builtin_amdgcn_mfma_f32_16x16x32_bf16(af[i], bfr[j], acc[i][j], 0, 0, 0);
  }
#pragma unroll
  for (int i = 0; i < 2; ++i)
#pragma unroll
    for (int j = 0; j < 2; ++j)
#pragma unroll
      for (int r = 0; r < 4; ++r) {
        int row = bm + wv * 32 + i * 16 + l4 * 4 + r;
        int col = j * 16 + l15;
        if (row < M) {
          float v = acc[i][j][r] + bias[col];
          v = v > 0.f ? v : (expf(v) - 1.f);
          Cout[(size_t)row * OUTC + col] = v;
        }
      }
}

// ------------------------------------------------------- attention dot scores
__global__ void k_att(const u16* __restrict__ hbuf, const float* __restrict__ asv,
                      const float* __restrict__ adv, float* __restrict__ a_s,
                      float* __restrict__ a_d) {
  int i = blockIdx.x * 256 + threadIdx.x;
  if (i >= NN * HH) return;
  int n = i >> 4, h = i & 15;
  const u16* hp = hbuf + (size_t)n * HC + h * CC;
  const float* sv = asv + h * CC;
  const float* dv = adv + h * CC;
  float ss = 0.f, dd = 0.f;
#pragma unroll
  for (int q = 0; q < 4; ++q) {
    short8v hv = *(const short8v*)(hp + q * 8);
#pragma unroll
    for (int j = 0; j < 8; ++j) {
      float v = bf2f((u16)hv[j]);
      int c = q * 8 + j;
      ss += v * sv[c];
      dd += v * dv[c];
    }
  }
  a_s[i] = ss;
  a_d[i] = dd;
}

// --------------------------------------------- fused softmax-stats + aggregation
// 1 wave per node, 4 nodes/block (NN % 4 == 0 -> no divergent exit).
// Phase A (lane = j*16+h): alpha -> LDS, wave-reduce m and denom.
// Phase B (h = lane>>2, coff=(lane&3)*8): edge loop with LDS softmax weights.
__global__ __launch_bounds__(256) void k_edge(const int* __restrict__ adj,
                                              const int* __restrict__ off,
                                              const float* __restrict__ a_s,
                                              const float* __restrict__ a_d,
                                              const u16* __restrict__ hbuf,
                                              const float* __restrict__ bias,
                                              float* __restrict__ outp) {
  __shared__ float exs[4][CAPD * 16];
  __shared__ float mls[4][16];
  __shared__ float ivs[4][16];
  const int wv = threadIdx.x >> 6, lane = threadIdx.x & 63;
  const int node = blockIdx.x * 4 + wv;
  float* exw = exs[wv];
  const int e0 = off[node], e1 = off[node + 1];

  {  // ---- phase A
    const int h = lane & 15, j = lane >> 4;
    const float adh = a_d[node * HH + h];
    float mx = -INFINITY;
    for (int p = e0 + j; p < e1; p += 4) {
      int s = adj[p];
      float a = a_s[s * HH + h] + adh;
      a = a > 0.f ? a : 0.2f * a;
      int q = p - e0;
      if (q < CAPD) exw[q * 16 + h] = a;
      mx = fmaxf(mx, a);
    }
    mx = fmaxf(mx, __shfl_xor(mx, 16));
    mx = fmaxf(mx, __shfl_xor(mx, 32));
    float sum = 0.f;
    for (int p = e0 + j; p < e1; p += 4) {
      int q = p - e0;
      float a;
      if (q < CAPD) {
        a = exw[q * 16 + h];
      } else {
        int s = adj[p];
        a = a_s[s * HH + h] + adh;
        a = a > 0.f ? a : 0.2f * a;
      }
      float e = __expf(a - mx);
      if (q < CAPD) exw[q * 16 + h] = e;
      sum += e;
    }
    sum += __shfl_xor(sum, 16);
    sum += __shfl_xor(sum, 32);
    if (j == 0) {
      mls[wv][h] = mx;
      ivs[wv][h] = 1.f / (sum + 1e-16f);
    }
  }
  __syncthreads();

  // ---- phase B
  const int h = lane >> 2, coff = (lane & 3) * 8;
  const float ivh = ivs[wv][h];
  float acc0[8] = {}, acc1[8] = {};
  int p = e0;
  for (; p + 2 <= e1; p += 2) {
    int q = p - e0;
    int s0 = adj[p], s1 = adj[p + 1];
    float w0, w1;
    if (q + 1 < CAPD) {
      w0 = exw[q * 16 + h];
      w1 = exw[(q + 1) * 16 + h];
    } else {  // rare: deg > CAPD fallback, recompute
      float adh = a_d[node * HH + h], mh = mls[wv][h];
      float a0 = a_s[s0 * HH + h] + adh; a0 = a0 > 0.f ? a0 : 0.2f * a0;
      float a1 = a_s[s1 * HH + h] + adh; a1 = a1 > 0.f ? a1 : 0.2f * a1;
      w0 = (q < CAPD) ? exw[q * 16 + h] : __expf(a0 - mh);
      w1 = __expf(a1 - mh);
    }
    short8v h0 = *(const short8v*)(hbuf + (size_t)s0 * HC + h * CC + coff);
    short8v h1 = *(const short8v*)(hbuf + (size_t)s1 * HC + h * CC + coff);
#pragma unroll
    for (int i = 0; i < 8; ++i) {
      acc0[i] = fmaf(w0, bf2f((u16)h0[i]), acc0[i]);
      acc1[i] = fmaf(w1, bf2f((u16)h1[i]), acc1[i]);
    }
  }
  if (p < e1) {
    int q = p - e0;
    int s0 = adj[p];
    float w0;
    if (q < CAPD) {
      w0 = exw[q * 16 + h];
    } else {
      float adh = a_d[node * HH + h];
      float a0 = a_s[s0 * HH + h] + adh; a0 = a0 > 0.f ? a0 : 0.2f * a0;
      w0 = __expf(a0 - mls[wv][h]);
    }
    short8v h0 = *(const short8v*)(hbuf + (size_t)s0 * HC + h * CC + coff);
#pragma unroll
    for (int i = 0; i < 8; ++i) acc0[i] = fmaf(w0, bf2f((u16)h0[i]), acc0[i]);
  }
  float accf[8];
#pragma unroll
  for (int i = 0; i < 8; ++i) accf[i] = (acc0[i] + acc1[i]) * ivh;
#pragma unroll
  for (int mk = 4; mk <= 32; mk <<= 1)
#pragma unroll
    for (int i = 0; i < 8; ++i) accf[i] += __shfl_xor(accf[i], mk);
  if (lane < 4) {
#pragma unroll
    for (int i = 0; i < 8; ++i) {
      int c = coff + i;
      float v = accf[i] * (1.f / 16.f) + bias[c];
      v = v > 0.f ? v : (expf(v) - 1.f);
      outp[(size_t)node * OUTC + c] = v;
    }
  }
}

// ---------------------------------------------------------------- launch
extern "C" void kernel_launch(void* const* d_in, const int* in_sizes, int n_in,
                              void* d_out, int out_size, void* d_ws, size_t ws_size,
                              hipStream_t stream) {
  const float* x = (const float*)d_in[0];
  const int* ei = (const int*)d_in[1];
  const float* W1 = (const float*)d_in[2];
  const float* att_src1 = (const float*)d_in[3];
  const float* att_dst1 = (const float*)d_in[4];
  const float* b1 = (const float*)d_in[5];
  const float* W2 = (const float*)d_in[6];
  const float* att_src2 = (const float*)d_in[7];
  const float* att_dst2 = (const float*)d_in[8];
  const float* b2 = (const float*)d_in[9];
  const float* lin1_w = (const float*)d_in[10];
  const float* lin1_b = (const float*)d_in[11];
  const float* lin2_w = (const float*)d_in[12];
  const float* lin2_b = (const float*)d_in[13];
  float* out = (float*)d_out;  // [x_in | x_out | x_self], each N*32

  char* w = (char*)d_ws;
  u16* h_buf = (u16*)w;     w += (size_t)NN * HC * 2;      // 20.48 MB
  u16* x_bf = (u16*)w;      w += (size_t)NN * FIN * 2;     // 10.24 MB
  u16* x1b = (u16*)w;       w += (size_t)NN * HIDN * 2;    // 5.12 MB
  u16* wt1 = (u16*)w;       w += (size_t)HC * FIN * 2;
  u16* wt2 = (u16*)w;       w += (size_t)HC * FIN * 2;
  u16* lt1 = (u16*)w;       w += (size_t)HIDN * FIN * 2;
  u16* lt2 = (u16*)w;       w += (size_t)OUTC * HIDN * 2;
  float* a_s = (float*)w;   w += (size_t)NN * HH * 4;
  float* a_d = (float*)w;   w += (size_t)NN * HH * 4;
  int* off1 = (int*)w;      w += (size_t)(NN + 1) * 4;
  int* off2 = (int*)w;      w += (size_t)(NN + 1) * 4;
  int* cur1 = (int*)w;      w += (size_t)NN * 4;
  int* cur2 = (int*)w;      w += (size_t)NN * 4;
  int* adj1 = (int*)w;      w += (size_t)EE * 4;
  int* adj2 = (int*)w;      w += (size_t)EE * 4;

  const int EB = (EE + 255) / 256;
  const int NB4 = NN / 4;           // 5000, exact
  const int MB = (NN + 127) / 128;  // 157

  // CSR build
  hipMemsetAsync(cur1, 0, (size_t)NN * 4, stream);
  hipMemsetAsync(cur2, 0, (size_t)NN * 4, stream);
  k_hist<<<EB, 256, 0, stream>>>(ei, cur1, cur2);
  k_scan<<<2, 1024, 0, stream>>>(cur1, off1, cur2, off2);
  k_scatter<<<EB, 256, 0, stream>>>(ei, cur1, cur2, adj1, adj2);

  // converts (one launch)
  k_prep<<<3668, 256, 0, stream>>>(x, x_bf, W1, wt1, W2, wt2, lin1_w, lt1, lin2_w, lt2);

  // conv1: messages from row0, aggregate at row1
  k_mfma_gemm<0, 1><<<dim3(MB, 4), 256, 0, stream>>>(x_bf, wt1, nullptr, h_buf, NN, FIN, HC);
  k_att<<<(NN * HH + 255) / 256, 256, 0, stream>>>(h_buf, att_src1, att_dst1, a_s, a_d);
  k_edge<<<NB4, 256, 0, stream>>>(adj1, off1, a_s, a_d, h_buf, b1, out);

  // conv2: messages from row1, aggregate at row0
  k_mfma_gemm<0, 1><<<dim3(MB, 4), 256, 0, stream>>>(x_bf, wt2, nullptr, h_buf, NN, FIN, HC);
  k_att<<<(NN * HH + 255) / 256, 256, 0, stream>>>(h_buf, att_src2, att_dst2, a_s, a_d);
  k_edge<<<NB4, 256, 0, stream>>>(adj2, off2, a_s, a_d, h_buf, b2,
                                  out + (size_t)NN * OUTC);

  // self path: x1b = elu(x@lin1 + b) bf16; x_self = elu(x1b@lin2 + b)
  k_mfma_gemm<1, 1><<<dim3(MB, 1), 256, 0, stream>>>(x_bf, lt1, lin1_b, x1b, NN, FIN, HIDN);
  k_mfma_n32<<<MB, 256, 0, stream>>>(x1b, lt2, lin2_b, out + (size_t)2 * NN * OUTC, NN);
}

// Round 5
// 317.992 us; speedup vs baseline: 2.1117x; 1.1191x over previous
//
#include <hip/hip_runtime.h>
#include <math.h>

#define NN 20000
#define EE 400000
#define FIN 256
#define HH 16
#define CC 32
#define HC 512    // H*C per conv
#define HW 1024   // h12 row width (conv1 | conv2)
#define HIDN 128
#define OUTC 32
#define NTOT 1152 // 512 + 512 + 128 mega-GEMM cols
#define CAPD 64   // per-node LDS edge capacity (deg ~ Poisson(20), P(>64)~1e-16)

typedef unsigned short u16;
typedef __attribute__((ext_vector_type(8))) short short8v;
typedef __attribute__((ext_vector_type(4))) float f32x4;

__device__ inline u16 f2bf(float f) {
  unsigned u = __builtin_bit_cast(unsigned, f);
  unsigned r = (u + 0x7fffu + ((u >> 16) & 1u)) >> 16;
  return (u16)r;
}
__device__ inline float bf2f(u16 b) {
  unsigned u = ((unsigned)b) << 16;
  return __builtin_bit_cast(float, u);
}

__device__ __forceinline__ void gload16(const u16* g, u16* l) {
  __builtin_amdgcn_global_load_lds(
      (const __attribute__((address_space(1))) unsigned int*)g,
      (__attribute__((address_space(3))) unsigned int*)l, 16, 0, 0);
}

// ---------------------------------------------------------------- graph build
__global__ void k_hist(const int* __restrict__ ei, int* cur) {
  int e = blockIdx.x * 256 + threadIdx.x;
  if (e < EE) {
    atomicAdd(&cur[ei[EE + e]], 1);       // conv1 aggregates at dst = row 1
    atomicAdd(&cur[NN + ei[e]], 1);       // conv2 aggregates at src = row 0
  }
}

__device__ void scan_one(int* cur, int* off, int* part) {
  const int t = threadIdx.x;
  const int CHK = 20;
  int base = t * CHK;
  int loc[CHK];
  int s = 0;
#pragma unroll
  for (int i = 0; i < CHK; ++i) {
    int idx = base + i;
    int v = (idx < NN) ? cur[idx] : 0;
    loc[i] = s;
    s += v;
  }
  part[t] = s;
  __syncthreads();
  for (int d = 1; d < 1024; d <<= 1) {
    int v2 = (t >= d) ? part[t - d] : 0;
    __syncthreads();
    part[t] += v2;
    __syncthreads();
  }
  int cbase = part[t] - s;
#pragma unroll
  for (int i = 0; i < CHK; ++i) {
    int idx = base + i;
    if (idx < NN) {
      int o = cbase + loc[i];
      off[idx] = o;
      cur[idx] = o;
    }
  }
  if (t == 1023) off[NN] = part[1023];
}

__global__ __launch_bounds__(1024) void k_scan(int* cur, int* off1, int* off2) {
  __shared__ int part[1024];
  if (blockIdx.x == 0) scan_one(cur, off1, part);
  else                 scan_one(cur + NN, off2, part);
}

__global__ void k_scatter(const int* __restrict__ ei, int* cur,
                          int* __restrict__ adj1, int* __restrict__ adj2) {
  int e = blockIdx.x * 256 + threadIdx.x;
  if (e < EE) {
    int s1 = ei[e], d1 = ei[EE + e];
    int p1 = atomicAdd(&cur[d1], 1);
    adj1[p1] = s1;                      // conv1: message source = row0
    int p2 = atomicAdd(&cur[NN + s1], 1);
    adj2[p2] = d1;                      // conv2: message source = row1
  }
}

// ---------------------------------------------------------- merged converts
// blocks [0,2500): x->bf16 ; [2500,3652): wtc rows (W1^T|W2^T|lin1^T) ;
// [3652,3668): lin2^T
__global__ void k_prep(const float* __restrict__ x, u16* __restrict__ xb,
                       const float* __restrict__ W1, const float* __restrict__ W2,
                       const float* __restrict__ L1, u16* __restrict__ wtc,
                       const float* __restrict__ L2, u16* __restrict__ lt2) {
  int b = blockIdx.x, t = threadIdx.x;
  if (b < 2500) {
    int i = b * 256 + t;
    float4 v0 = ((const float4*)x)[i * 2];
    float4 v1 = ((const float4*)x)[i * 2 + 1];
    short8v o;
    o[0] = (short)f2bf(v0.x); o[1] = (short)f2bf(v0.y);
    o[2] = (short)f2bf(v0.z); o[3] = (short)f2bf(v0.w);
    o[4] = (short)f2bf(v1.x); o[5] = (short)f2bf(v1.y);
    o[6] = (short)f2bf(v1.z); o[7] = (short)f2bf(v1.w);
    *(short8v*)(xb + (size_t)i * 8) = o;
  } else if (b < 3652) {
    int i = (b - 2500) * 256 + t;   // [NTOT][256]
    int n = i >> 8, k = i & 255;
    float v;
    if (n < 512)       v = W1[k * HC + n];
    else if (n < 1024) v = W2[k * HC + (n - 512)];
    else               v = L1[k * HIDN + (n - 1024)];
    wtc[i] = f2bf(v);
  } else {
    int i = (b - 3652) * 256 + t;   // [32][128]
    int n = i >> 7, k = i & 127;
    lt2[i] = f2bf(L2[k * OUTC + n]);
  }
}

// ------------------------------------------------- mega bf16 MFMA GEMM (N=1152)
// C = x_bf[M,256] @ wtc[1152,256]^T. 128x128 tile, BK=64, 4 waves 2x2 of 64x64.
// bn<8 -> h12 (bf16, stride 1024); bn==8 -> x1b = elu(.+lin1_b) (bf16, stride 128)
__global__ __launch_bounds__(256) void k_gemm_big(const u16* __restrict__ A,
                                                  const u16* __restrict__ Bt,
                                                  const float* __restrict__ lin1_b,
                                                  u16* __restrict__ h12,
                                                  u16* __restrict__ x1b) {
  __shared__ u16 As[128 * 64];
  __shared__ u16 Bs[128 * 64];
  const int t = threadIdx.x;
  const int lane = t & 63, wave = t >> 6;
  const int wr = (wave >> 1) * 64, wc = (wave & 1) * 64;
  const int bm = blockIdx.x * 128, bn = blockIdx.y;
  const int l15 = lane & 15, l4 = lane >> 4;
  const int rloc = lane >> 3;
  const int kc_src = (lane & 7) ^ rloc;
  const int K = FIN;

  f32x4 acc[4][4] = {};

  for (int k0 = 0; k0 < K; k0 += 64) {
    __syncthreads();
#pragma unroll
    for (int q = 0; q < 4; ++q) {
      const int rblk = q * 4 + wave;
      const int r = rblk * 8 + rloc;
      gload16(A + (size_t)(bm + r) * K + k0 + kc_src * 8, As + rblk * 512);
      gload16(Bt + (size_t)(bn * 128 + r) * K + k0 + kc_src * 8, Bs + rblk * 512);
    }
    __syncthreads();
#pragma unroll
    for (int kh = 0; kh < 2; ++kh) {
      const int kc = kh * 4 + l4;
      short8v af[4], bfr[4];
#pragma unroll
      for (int i = 0; i < 4; ++i) {
        int row = wr + i * 16 + l15;
        af[i] = *(const short8v*)(As + row * 64 + (kc ^ (row & 7)) * 8);
      }
#pragma unroll
      for (int j = 0; j < 4; ++j) {
        int row = wc + j * 16 + l15;
        bfr[j] = *(const short8v*)(Bs + row * 64 + (kc ^ (row & 7)) * 8);
      }
#pragma unroll
      for (int i = 0; i < 4; ++i)
#pragma unroll
        for (int j = 0; j < 4; ++j)
          acc[i][j] = __builtin_amdgcn_mfma_f32_16x16x32_bf16(af[i], bfr[j], acc[i][j], 0, 0, 0);
    }
  }

#pragma unroll
  for (int i = 0; i < 4; ++i)
#pragma unroll
    for (int j = 0; j < 4; ++j)
#pragma unroll
      for (int r = 0; r < 4; ++r) {
        int row = bm + wr + i * 16 + l4 * 4 + r;
        if (row >= NN) continue;
        int colb = bn * 128 + wc + j * 16 + l15;
        float v = acc[i][j][r];
        if (bn < 8) {
          h12[(size_t)row * HW + colb] = f2bf(v);
        } else {
          int c = colb - 1024;
          v += lin1_b[c];
          v = v > 0.f ? v : (expf(v) - 1.f);
          x1b[(size_t)row * HIDN + c] = f2bf(v);
        }
      }
}

// MFMA GEMM for Nc=32, K=128 (lin2): 128x32 tile, 4 waves each 32 rows.
__global__ __launch_bounds__(256) void k_mfma_n32(const u16* __restrict__ A,
                                                  const u16* __restrict__ Bt,
                                                  const float* __restrict__ bias,
                                                  float* __restrict__ Cout, int M) {
  __shared__ u16 As[128 * 40];
  __shared__ u16 Bs[32 * 40];
  const int t = threadIdx.x;
  const int lane = t & 63, wv = t >> 6;
  const int bm = blockIdx.x * 128;
  const int l15 = lane & 15, l4 = lane >> 4;
  const int srow = t >> 2, skoff = (t & 3) * 8;
  int aR0 = bm + srow;        if (aR0 >= M) aR0 = M - 1;
  int aR1 = bm + 64 + srow;   if (aR1 >= M) aR1 = M - 1;

  f32x4 acc[2][2] = {};

  for (int k0 = 0; k0 < 128; k0 += 32) {
    short8v a0 = *(const short8v*)(A + (size_t)aR0 * 128 + k0 + skoff);
    short8v a1 = *(const short8v*)(A + (size_t)aR1 * 128 + k0 + skoff);
    short8v b0 = {};
    if (t < 128) b0 = *(const short8v*)(Bt + (size_t)(t >> 2) * 128 + k0 + skoff);
    __syncthreads();
    *(short8v*)(As + srow * 40 + skoff) = a0;
    *(short8v*)(As + (64 + srow) * 40 + skoff) = a1;
    if (t < 128) *(short8v*)(Bs + (t >> 2) * 40 + skoff) = b0;
    __syncthreads();
    short8v af[2], bfr[2];
#pragma unroll
    for (int i = 0; i < 2; ++i)
      af[i] = *(const short8v*)(As + (wv * 32 + i * 16 + l15) * 40 + l4 * 8);
#pragma unroll
    for (int j = 0; j < 2; ++j)
      bfr[j] = *(const short8v*)(Bs + (j * 16 + l15) * 40 + l4 * 8);
#pragma unroll
    for (int i = 0; i < 2; ++i)
#pragma unroll
      for (int j = 0; j < 2; ++j)
        acc[i][j] = __builtin_amdgcn_mfma_f32_16x16x32_bf16(af[i], bfr[j], acc[i][j], 0, 0, 0);
  }
#pragma unroll
  for (int i = 0; i < 2; ++i)
#pragma unroll
    for (int j = 0; j < 2; ++j)
#pragma unroll
      for (int r = 0; r < 4; ++r) {
        int row = bm + wv * 32 + i * 16 + l4 * 4 + r;
        int col = j * 16 + l15;
        if (row < M) {
          float v = acc[i][j][r] + bias[col];
          v = v > 0.f ? v : (expf(v) - 1.f);
          Cout[(size_t)row * OUTC + col] = v;
        }
      }
}

// ----------------------------------------- attention dot scores (both convs)
__global__ void k_att(const u16* __restrict__ h12,
                      const float* __restrict__ as1, const float* __restrict__ ad1,
                      const float* __restrict__ as2, const float* __restrict__ ad2,
                      float* __restrict__ a_sA, float* __restrict__ a_dA) {
  int i = blockIdx.x * 256 + threadIdx.x;   // i in [0, 2*NN*HH)
  int conv = i >= NN * HH;
  int ii = i - conv * NN * HH;
  int n = ii >> 4, h = ii & 15;
  const u16* hp = h12 + (size_t)n * HW + conv * HC + h * CC;
  const float* sv = (conv ? as2 : as1) + h * CC;
  const float* dv = (conv ? ad2 : ad1) + h * CC;
  float ss = 0.f, dd = 0.f;
#pragma unroll
  for (int q = 0; q < 4; ++q) {
    short8v hv = *(const short8v*)(hp + q * 8);
#pragma unroll
    for (int j = 0; j < 8; ++j) {
      float v = bf2f((u16)hv[j]);
      int c = q * 8 + j;
      ss += v * sv[c];
      dd += v * dv[c];
    }
  }
  a_sA[i] = ss;
  a_dA[i] = dd;
}

// ---------------------- fused softmax-stats + aggregation, both convs, one grid
// blocks [0,5000): conv1 ; [5000,10000): conv2.  1 wave/node, 4 nodes/block.
__global__ __launch_bounds__(256) void k_edge(const int* __restrict__ adj1,
                                              const int* __restrict__ off1,
                                              const int* __restrict__ adj2,
                                              const int* __restrict__ off2,
                                              const float* __restrict__ a_sA,
                                              const float* __restrict__ a_dA,
                                              const u16* __restrict__ h12,
                                              const float* __restrict__ b1,
                                              const float* __restrict__ b2,
                                              float* __restrict__ out) {
  __shared__ float exs[4][CAPD * 16];
  __shared__ float mls[4][16];
  __shared__ float ivs[4][16];
  const int wv = threadIdx.x >> 6, lane = threadIdx.x & 63;
  const int conv = blockIdx.x >= (NN / 4);
  const int node = (blockIdx.x - conv * (NN / 4)) * 4 + wv;
  const int* __restrict__ adj = conv ? adj2 : adj1;
  const int* __restrict__ off = conv ? off2 : off1;
  const float* __restrict__ a_s = a_sA + (size_t)conv * NN * HH;
  const float* __restrict__ a_d = a_dA + (size_t)conv * NN * HH;
  const u16* __restrict__ hbase = h12 + conv * HC;
  const float* __restrict__ bias = conv ? b2 : b1;
  float* __restrict__ outp = out + (size_t)conv * NN * OUTC;

  float* exw = exs[wv];
  const int e0 = off[node], e1 = off[node + 1];

  {  // ---- phase A: alpha -> LDS (f32), wave-reduce max & denom
    const int h = lane & 15, j = lane >> 4;
    const float adh = a_d[node * HH + h];
    float mx = -INFINITY;
    for (int p = e0 + j; p < e1; p += 4) {
      int s = adj[p];
      float a = a_s[s * HH + h] + adh;
      a = a > 0.f ? a : 0.2f * a;
      int q = p - e0;
      if (q < CAPD) exw[q * 16 + h] = a;
      mx = fmaxf(mx, a);
    }
    mx = fmaxf(mx, __shfl_xor(mx, 16));
    mx = fmaxf(mx, __shfl_xor(mx, 32));
    float sum = 0.f;
    for (int p = e0 + j; p < e1; p += 4) {
      int q = p - e0;
      float a;
      if (q < CAPD) {
        a = exw[q * 16 + h];
      } else {
        int s = adj[p];
        a = a_s[s * HH + h] + adh;
        a = a > 0.f ? a : 0.2f * a;
      }
      float e = __expf(a - mx);
      if (q < CAPD) exw[q * 16 + h] = e;
      sum += e;
    }
    sum += __shfl_xor(sum, 16);
    sum += __shfl_xor(sum, 32);
    if (j == 0) {
      mls[wv][h] = mx;
      ivs[wv][h] = 1.f / (sum + 1e-16f);
    }
  }
  __syncthreads();

  // ---- phase B: h-gather aggregation
  const int h = lane >> 2, coff = (lane & 3) * 8;
  const float ivh = ivs[wv][h];
  float acc0[8] = {}, acc1[8] = {};
  int p = e0;
  for (; p + 2 <= e1; p += 2) {
    int q = p - e0;
    int s0 = adj[p], s1 = adj[p + 1];
    float w0, w1;
    if (q + 1 < CAPD) {
      w0 = exw[q * 16 + h];
      w1 = exw[(q + 1) * 16 + h];
    } else {  // rare deg > CAPD fallback
      float adh = a_d[node * HH + h], mh = mls[wv][h];
      float aa0 = a_s[s0 * HH + h] + adh; aa0 = aa0 > 0.f ? aa0 : 0.2f * aa0;
      float aa1 = a_s[s1 * HH + h] + adh; aa1 = aa1 > 0.f ? aa1 : 0.2f * aa1;
      w0 = (q < CAPD) ? exw[q * 16 + h] : __expf(aa0 - mh);
      w1 = __expf(aa1 - mh);
    }
    short8v h0 = *(const short8v*)(hbase + (size_t)s0 * HW + h * CC + coff);
    short8v h1 = *(const short8v*)(hbase + (size_t)s1 * HW + h * CC + coff);
#pragma unroll
    for (int i = 0; i < 8; ++i) {
      acc0[i] = fmaf(w0, bf2f((u16)h0[i]), acc0[i]);
      acc1[i] = fmaf(w1, bf2f((u16)h1[i]), acc1[i]);
    }
  }
  if (p < e1) {
    int q = p - e0;
    int s0 = adj[p];
    float w0;
    if (q < CAPD) {
      w0 = exw[q * 16 + h];
    } else {
      float adh = a_d[node * HH + h];
      float aa0 = a_s[s0 * HH + h] + adh; aa0 = aa0 > 0.f ? aa0 : 0.2f * aa0;
      w0 = __expf(aa0 - mls[wv][h]);
    }
    short8v h0 = *(const short8v*)(hbase + (size_t)s0 * HW + h * CC + coff);
#pragma unroll
    for (int i = 0; i < 8; ++i) acc0[i] = fmaf(w0, bf2f((u16)h0[i]), acc0[i]);
  }
  float accf[8];
#pragma unroll
  for (int i = 0; i < 8; ++i) accf[i] = (acc0[i] + acc1[i]) * ivh;
#pragma unroll
  for (int mk = 4; mk <= 32; mk <<= 1)
#pragma unroll
    for (int i = 0; i < 8; ++i) accf[i] += __shfl_xor(accf[i], mk);
  if (lane < 4) {
#pragma unroll
    for (int i = 0; i < 8; ++i) {
      int c = coff + i;
      float v = accf[i] * (1.f / 16.f) + bias[c];
      v = v > 0.f ? v : (expf(v) - 1.f);
      outp[(size_t)node * OUTC + c] = v;
    }
  }
}

// ---------------------------------------------------------------- launch
extern "C" void kernel_launch(void* const* d_in, const int* in_sizes, int n_in,
                              void* d_out, int out_size, void* d_ws, size_t ws_size,
                              hipStream_t stream) {
  const float* x = (const float*)d_in[0];
  const int* ei = (const int*)d_in[1];
  const float* W1 = (const float*)d_in[2];
  const float* att_src1 = (const float*)d_in[3];
  const float* att_dst1 = (const float*)d_in[4];
  const float* b1 = (const float*)d_in[5];
  const float* W2 = (const float*)d_in[6];
  const float* att_src2 = (const float*)d_in[7];
  const float* att_dst2 = (const float*)d_in[8];
  const float* b2 = (const float*)d_in[9];
  const float* lin1_w = (const float*)d_in[10];
  const float* lin1_b = (const float*)d_in[11];
  const float* lin2_w = (const float*)d_in[12];
  const float* lin2_b = (const float*)d_in[13];
  float* out = (float*)d_out;  // [x_in | x_out | x_self], each N*32

  char* w = (char*)d_ws;
  u16* h12 = (u16*)w;       w += (size_t)NN * HW * 2;      // 40.96 MB
  u16* x_bf = (u16*)w;      w += (size_t)NN * FIN * 2;     // 10.24 MB
  u16* x1b = (u16*)w;       w += (size_t)NN * HIDN * 2;    // 5.12 MB
  u16* wtc = (u16*)w;       w += (size_t)NTOT * FIN * 2;   // 0.59 MB
  u16* lt2 = (u16*)w;       w += (size_t)OUTC * HIDN * 2;
  float* a_sA = (float*)w;  w += (size_t)2 * NN * HH * 4;  // 2.56 MB
  float* a_dA = (float*)w;  w += (size_t)2 * NN * HH * 4;
  int* off1 = (int*)w;      w += (size_t)(NN + 1) * 4;
  int* off2 = (int*)w;      w += (size_t)(NN + 1) * 4;
  int* cur = (int*)w;       w += (size_t)2 * NN * 4;       // cur1|cur2 adjacent
  int* adj1 = (int*)w;      w += (size_t)EE * 4;
  int* adj2 = (int*)w;      w += (size_t)EE * 4;

  const int EB = (EE + 255) / 256;
  const int MB = (NN + 127) / 128;  // 157

  // CSR build
  hipMemsetAsync(cur, 0, (size_t)2 * NN * 4, stream);
  k_hist<<<EB, 256, 0, stream>>>(ei, cur);
  k_scan<<<2, 1024, 0, stream>>>(cur, off1, off2);
  k_scatter<<<EB, 256, 0, stream>>>(ei, cur, adj1, adj2);

  // converts (one launch)
  k_prep<<<3668, 256, 0, stream>>>(x, x_bf, W1, W2, lin1_w, wtc, lin2_w, lt2);

  // mega GEMM: h12 (conv1|conv2) + x1b = elu(x@lin1+b)
  k_gemm_big<<<dim3(MB, 9), 256, 0, stream>>>(x_bf, wtc, lin1_b, h12, x1b);

  // attention scores, both convs
  k_att<<<(2 * NN * HH) / 256, 256, 0, stream>>>(h12, att_src1, att_dst1,
                                                 att_src2, att_dst2, a_sA, a_dA);

  // x_self = elu(x1b@lin2 + b)
  k_mfma_n32<<<MB, 256, 0, stream>>>(x1b, lt2, lin2_b, out + (size_t)2 * NN * OUTC, NN);

  // fused softmax+aggregation, both convs
  k_edge<<<2 * (NN / 4), 256, 0, stream>>>(adj1, off1, adj2, off2, a_sA, a_dA,
                                           h12, b1, b2, out);
}

// Round 6
// 295.838 us; speedup vs baseline: 2.2698x; 1.0749x over previous
//
#include <hip/hip_runtime.h>
#include <math.h>

#define NN 20000
#define EE 400000
#define FIN 256
#define HH 16
#define CC 32
#define HC 512    // H*C per conv
#define HW 1024   // h12 row width (conv1 | conv2)
#define HIDN 128
#define OUTC 32
#define WT 1024   // wtc rows (W1^T | W2^T)
#define CAPD 64   // per-node LDS edge capacity (deg ~ Poisson(20), P(>64)~1e-16)

typedef unsigned short u16;
typedef __attribute__((ext_vector_type(8))) short short8v;
typedef __attribute__((ext_vector_type(4))) float f32x4;

__device__ inline u16 f2bf(float f) {
  unsigned u = __builtin_bit_cast(unsigned, f);
  unsigned r = (u + 0x7fffu + ((u >> 16) & 1u)) >> 16;
  return (u16)r;
}
__device__ inline float bf2f(u16 b) {
  unsigned u = ((unsigned)b) << 16;
  return __builtin_bit_cast(float, u);
}

__device__ __forceinline__ void gload16(const u16* g, u16* l) {
  __builtin_amdgcn_global_load_lds(
      (const __attribute__((address_space(1))) unsigned int*)g,
      (__attribute__((address_space(3))) unsigned int*)l, 16, 0, 0);
}

// ---------------------------------------------------------------- graph build
__global__ void k_hist(const int* __restrict__ ei, int* cur) {
  int e = blockIdx.x * 256 + threadIdx.x;
  if (e < EE) {
    atomicAdd(&cur[ei[EE + e]], 1);       // conv1 aggregates at dst = row 1
    atomicAdd(&cur[NN + ei[e]], 1);       // conv2 aggregates at src = row 0
  }
}

__device__ void scan_one(int* cur, int* off, int* part) {
  const int t = threadIdx.x;
  const int CHK = 20;
  int base = t * CHK;
  int loc[CHK];
  int s = 0;
#pragma unroll
  for (int i = 0; i < CHK; ++i) {
    int idx = base + i;
    int v = (idx < NN) ? cur[idx] : 0;
    loc[i] = s;
    s += v;
  }
  part[t] = s;
  __syncthreads();
  for (int d = 1; d < 1024; d <<= 1) {
    int v2 = (t >= d) ? part[t - d] : 0;
    __syncthreads();
    part[t] += v2;
    __syncthreads();
  }
  int cbase = part[t] - s;
#pragma unroll
  for (int i = 0; i < CHK; ++i) {
    int idx = base + i;
    if (idx < NN) {
      int o = cbase + loc[i];
      off[idx] = o;
      cur[idx] = o;
    }
  }
  if (t == 1023) off[NN] = part[1023];
}

__global__ __launch_bounds__(1024) void k_scan(int* cur, int* off1, int* off2) {
  __shared__ int part[1024];
  if (blockIdx.x == 0) scan_one(cur, off1, part);
  else                 scan_one(cur + NN, off2, part);
}

__global__ void k_scatter(const int* __restrict__ ei, int* cur,
                          int* __restrict__ adj1, int* __restrict__ adj2) {
  int e = blockIdx.x * 256 + threadIdx.x;
  if (e < EE) {
    int s1 = ei[e], d1 = ei[EE + e];
    int p1 = atomicAdd(&cur[d1], 1);
    adj1[p1] = s1;                      // conv1: message source = row0
    int p2 = atomicAdd(&cur[NN + s1], 1);
    adj2[p2] = d1;                      // conv2: message source = row1
  }
}

// ---------------------------------------------------------- merged converts
// [0,2500): x->bf16 ; [2500,3524): wtc (W1^T|W2^T) ; [3524,3652): lt1 ; [3652,3668): lt2
__global__ void k_prep(const float* __restrict__ x, u16* __restrict__ xb,
                       const float* __restrict__ W1, const float* __restrict__ W2,
                       u16* __restrict__ wtc,
                       const float* __restrict__ L1, u16* __restrict__ lt1,
                       const float* __restrict__ L2, u16* __restrict__ lt2) {
  int b = blockIdx.x, t = threadIdx.x;
  if (b < 2500) {
    int i = b * 256 + t;
    float4 v0 = ((const float4*)x)[i * 2];
    float4 v1 = ((const float4*)x)[i * 2 + 1];
    short8v o;
    o[0] = (short)f2bf(v0.x); o[1] = (short)f2bf(v0.y);
    o[2] = (short)f2bf(v0.z); o[3] = (short)f2bf(v0.w);
    o[4] = (short)f2bf(v1.x); o[5] = (short)f2bf(v1.y);
    o[6] = (short)f2bf(v1.z); o[7] = (short)f2bf(v1.w);
    *(short8v*)(xb + (size_t)i * 8) = o;
  } else if (b < 3524) {
    int i = (b - 2500) * 256 + t;   // [1024][256]
    int n = i >> 8, k = i & 255;
    wtc[i] = f2bf(n < 512 ? W1[k * HC + n] : W2[k * HC + (n - 512)]);
  } else if (b < 3652) {
    int i = (b - 3524) * 256 + t;   // [128][256]
    int n = i >> 8, k = i & 255;
    lt1[i] = f2bf(L1[k * HIDN + n]);
  } else {
    int i = (b - 3652) * 256 + t;   // [32][128]
    int n = i >> 7, k = i & 127;
    lt2[i] = f2bf(L2[k * OUTC + n]);
  }
}

// ------------------------------------------------- mega bf16 MFMA GEMM (N=1024)
// h12 = x_bf[M,256] @ wtc[1024,256]^T, plus fused a_s/a_d epilogue.
// 1D grid 1256 = 157 bm x 8 bn; XCD-chunked: hw%8 -> contiguous logical range.
__global__ __launch_bounds__(256) void k_gemm_big(const u16* __restrict__ A,
                                                  const u16* __restrict__ Bt,
                                                  const float* __restrict__ as1,
                                                  const float* __restrict__ ad1,
                                                  const float* __restrict__ as2,
                                                  const float* __restrict__ ad2,
                                                  u16* __restrict__ h12,
                                                  float* __restrict__ a_sA,
                                                  float* __restrict__ a_dA) {
  __shared__ u16 As[128 * 64];
  __shared__ u16 Bs[128 * 64];
  const int hw = blockIdx.x;
  const int logical = (hw & 7) * 157 + (hw >> 3);   // 1256 = 8*157 exact
  const int bm = (logical >> 3) * 128, bn = logical & 7;
  const int t = threadIdx.x;
  const int lane = t & 63, wave = t >> 6;
  const int wr = (wave >> 1) * 64, wc = (wave & 1) * 64;
  const int l15 = lane & 15, l4 = lane >> 4;
  const int rloc = lane >> 3;
  const int kc_src = (lane & 7) ^ rloc;
  const int K = FIN;

  f32x4 acc[4][4] = {};

  for (int k0 = 0; k0 < K; k0 += 64) {
    __syncthreads();
#pragma unroll
    for (int q = 0; q < 4; ++q) {
      const int rblk = q * 4 + wave;
      const int r = rblk * 8 + rloc;
      gload16(A + (size_t)(bm + r) * K + k0 + kc_src * 8, As + rblk * 512);
      gload16(Bt + (size_t)(bn * 128 + r) * K + k0 + kc_src * 8, Bs + rblk * 512);
    }
    __syncthreads();
#pragma unroll
    for (int kh = 0; kh < 2; ++kh) {
      const int kc = kh * 4 + l4;
      short8v af[4], bfr[4];
#pragma unroll
      for (int i = 0; i < 4; ++i) {
        int row = wr + i * 16 + l15;
        af[i] = *(const short8v*)(As + row * 64 + (kc ^ (row & 7)) * 8);
      }
#pragma unroll
      for (int j = 0; j < 4; ++j) {
        int row = wc + j * 16 + l15;
        bfr[j] = *(const short8v*)(Bs + row * 64 + (kc ^ (row & 7)) * 8);
      }
#pragma unroll
      for (int i = 0; i < 4; ++i)
#pragma unroll
        for (int j = 0; j < 4; ++j)
          acc[i][j] = __builtin_amdgcn_mfma_f32_16x16x32_bf16(af[i], bfr[j], acc[i][j], 0, 0, 0);
    }
  }

  const int conv = bn >> 2;
  // h12 writes
#pragma unroll
  for (int i = 0; i < 4; ++i)
#pragma unroll
    for (int j = 0; j < 4; ++j)
#pragma unroll
      for (int r = 0; r < 4; ++r) {
        int row = bm + wr + i * 16 + l4 * 4 + r;
        if (row >= NN) continue;
        int colb = bn * 128 + wc + j * 16 + l15;
        h12[(size_t)row * HW + colb] = f2bf(acc[i][j][r]);
      }

  // fused a_s/a_d: wave covers heads hA (j=0,1) and hA+1 (j=2,3)
  float asv[4], adv[4];
#pragma unroll
  for (int j = 0; j < 4; ++j) {
    int lc = (bn & 3) * 128 + wc + j * 16 + l15;  // 0..511 within conv
    int hh = lc >> 5, c = lc & 31;
    asv[j] = (conv ? as2 : as1)[hh * CC + c];
    adv[j] = (conv ? ad2 : ad1)[hh * CC + c];
  }
  const int hA = (bn & 3) * 4 + (wc >> 5);  // even
  float* aS = a_sA + (size_t)conv * NN * HH;
  float* aD = a_dA + (size_t)conv * NN * HH;
#pragma unroll
  for (int i = 0; i < 4; ++i)
#pragma unroll
    for (int r = 0; r < 4; ++r) {
      float sAs = acc[i][0][r] * asv[0] + acc[i][1][r] * asv[1];
      float sAd = acc[i][0][r] * adv[0] + acc[i][1][r] * adv[1];
      float sBs = acc[i][2][r] * asv[2] + acc[i][3][r] * asv[3];
      float sBd = acc[i][2][r] * adv[2] + acc[i][3][r] * adv[3];
#pragma unroll
      for (int m = 1; m < 16; m <<= 1) {
        sAs += __shfl_xor(sAs, m);
        sAd += __shfl_xor(sAd, m);
        sBs += __shfl_xor(sBs, m);
        sBd += __shfl_xor(sBd, m);
      }
      int row = bm + wr + i * 16 + l4 * 4 + r;
      if (l15 == 0 && row < NN) {
        *(float2*)(aS + (size_t)row * HH + hA) = make_float2(sAs, sBs);
        *(float2*)(aD + (size_t)row * HH + hA) = make_float2(sAd, sBd);
      }
    }
}

// --------------------------- self path: out3 = elu(elu(x@lin1+b)@lin2+b)
__global__ __launch_bounds__(256) void k_self(const u16* __restrict__ A,
                                              const u16* __restrict__ lt1,
                                              const u16* __restrict__ lt2,
                                              const float* __restrict__ lin1_b,
                                              const float* __restrict__ lin2_b,
                                              float* __restrict__ outp) {
  __shared__ u16 smem[128 * 136];  // aliased: As|Bs during GEMM1, x1 tile after
  u16* As = smem;
  u16* Bs = smem + 128 * 64;
  const int t = threadIdx.x;
  const int lane = t & 63, wave = t >> 6;
  const int wr = (wave >> 1) * 64, wc = (wave & 1) * 64;
  const int bm = blockIdx.x * 128;
  const int l15 = lane & 15, l4 = lane >> 4;
  const int rloc = lane >> 3;
  const int kc_src = (lane & 7) ^ rloc;
  const int K = FIN;

  f32x4 acc[4][4] = {};
  for (int k0 = 0; k0 < K; k0 += 64) {
    __syncthreads();
#pragma unroll
    for (int q = 0; q < 4; ++q) {
      const int rblk = q * 4 + wave;
      const int r = rblk * 8 + rloc;
      gload16(A + (size_t)(bm + r) * K + k0 + kc_src * 8, As + rblk * 512);
      gload16(lt1 + (size_t)r * K + k0 + kc_src * 8, Bs + rblk * 512);
    }
    __syncthreads();
#pragma unroll
    for (int kh = 0; kh < 2; ++kh) {
      const int kc = kh * 4 + l4;
      short8v af[4], bfr[4];
#pragma unroll
      for (int i = 0; i < 4; ++i) {
        int row = wr + i * 16 + l15;
        af[i] = *(const short8v*)(As + row * 64 + (kc ^ (row & 7)) * 8);
      }
#pragma unroll
      for (int j = 0; j < 4; ++j) {
        int row = wc + j * 16 + l15;
        bfr[j] = *(const short8v*)(Bs + row * 64 + (kc ^ (row & 7)) * 8);
      }
#pragma unroll
      for (int i = 0; i < 4; ++i)
#pragma unroll
        for (int j = 0; j < 4; ++j)
          acc[i][j] = __builtin_amdgcn_mfma_f32_16x16x32_bf16(af[i], bfr[j], acc[i][j], 0, 0, 0);
    }
  }

  __syncthreads();  // done reading As/Bs; reuse smem as x1 tile [128][136]
#pragma unroll
  for (int i = 0; i < 4; ++i)
#pragma unroll
    for (int j = 0; j < 4; ++j)
#pragma unroll
      for (int r = 0; r < 4; ++r) {
        int row = wr + i * 16 + l4 * 4 + r;
        int col = wc + j * 16 + l15;
        float v = acc[i][j][r] + lin1_b[col];
        v = v > 0.f ? v : (expf(v) - 1.f);
        smem[row * 136 + col] = f2bf(v);
      }
  __syncthreads();

  // GEMM2: [128 rows] x lt2[32][128]^T, wave wv -> rows [wv*32, wv*32+32)
  f32x4 acc2[2][2] = {};
#pragma unroll
  for (int kk = 0; kk < 4; ++kk) {
    short8v af[2], bfr[2];
#pragma unroll
    for (int i = 0; i < 2; ++i)
      af[i] = *(const short8v*)(smem + (wave * 32 + i * 16 + l15) * 136 + kk * 32 + l4 * 8);
#pragma unroll
    for (int j = 0; j < 2; ++j)
      bfr[j] = *(const short8v*)(lt2 + (size_t)(j * 16 + l15) * 128 + kk * 32 + l4 * 8);
#pragma unroll
    for (int i = 0; i < 2; ++i)
#pragma unroll
      for (int j = 0; j < 2; ++j)
        acc2[i][j] = __builtin_amdgcn_mfma_f32_16x16x32_bf16(af[i], bfr[j], acc2[i][j], 0, 0, 0);
  }
#pragma unroll
  for (int i = 0; i < 2; ++i)
#pragma unroll
    for (int j = 0; j < 2; ++j)
#pragma unroll
      for (int r = 0; r < 4; ++r) {
        int row = bm + wave * 32 + i * 16 + l4 * 4 + r;
        int col = j * 16 + l15;
        if (row < NN) {
          float v = acc2[i][j][r] + lin2_b[col];
          v = v > 0.f ? v : (expf(v) - 1.f);
          outp[(size_t)row * OUTC + col] = v;
        }
      }
}

// ---------------------- fused softmax + aggregation, both convs, independent waves
// grid 10000 x 256; wave w of block b handles gid = b*4+w (conv = gid>=NN).
// No __syncthreads: each wave uses only its own LDS slice (wave-synchronous).
__global__ __launch_bounds__(256) void k_edge(const int* __restrict__ adj1,
                                              const int* __restrict__ off1,
                                              const int* __restrict__ adj2,
                                              const int* __restrict__ off2,
                                              const float* __restrict__ a_sA,
                                              const float* __restrict__ a_dA,
                                              const u16* __restrict__ h12,
                                              const float* __restrict__ b1,
                                              const float* __restrict__ b2,
                                              float* __restrict__ out) {
  __shared__ float exs[4][CAPD * 16];
  const int wv = threadIdx.x >> 6, lane = threadIdx.x & 63;
  const int gid = blockIdx.x * 4 + wv;
  const int conv = gid >= NN;
  const int node = gid - conv * NN;
  const int* __restrict__ adj = conv ? adj2 : adj1;
  const int* __restrict__ off = conv ? off2 : off1;
  const float* __restrict__ a_s = a_sA + (size_t)conv * NN * HH;
  const float* __restrict__ a_d = a_dA + (size_t)conv * NN * HH;
  const u16* __restrict__ hbase = h12 + conv * HC;
  const float* __restrict__ bias = conv ? b2 : b1;
  float* __restrict__ outp = out + (size_t)conv * NN * OUTC;
  float* exw = exs[wv];
  const int e0 = off[node], e1 = off[node + 1];
  const int deg = e1 - e0;

  float mx = -INFINITY, sum = 0.f;
  float adh_a;
  {  // ---- phase A: alpha -> LDS (f32), wave-reduce max & denom
    const int ha = lane & 15, j = lane >> 4;
    adh_a = a_d[node * HH + ha];
    for (int p = e0 + j; p < e1; p += 4) {
      int s = adj[p];
      float a = a_s[s * HH + ha] + adh_a;
      a = a > 0.f ? a : 0.2f * a;
      int q = p - e0;
      if (q < CAPD) exw[q * 16 + ha] = a;
      mx = fmaxf(mx, a);
    }
    mx = fmaxf(mx, __shfl_xor(mx, 16));
    mx = fmaxf(mx, __shfl_xor(mx, 32));
    for (int p = e0 + j; p < e1; p += 4) {
      int q = p - e0;
      float a;
      if (q < CAPD) {
        a = exw[q * 16 + ha];
      } else {
        int s = adj[p];
        a = a_s[s * HH + ha] + adh_a;
        a = a > 0.f ? a : 0.2f * a;
      }
      float e = __expf(a - mx);
      if (q < CAPD) exw[q * 16 + ha] = e;
      sum += e;
    }
    sum += __shfl_xor(sum, 16);
    sum += __shfl_xor(sum, 32);
  }
  __builtin_amdgcn_wave_barrier();
  __asm__ volatile("" ::: "memory");

  // ---- phase B: h-gather aggregation (h = lane>>2, 8 channels/lane)
  const int h = lane >> 2, coff = (lane & 3) * 8;
  const float mxh = __shfl(mx, h);
  const float ivh = __shfl(1.f / (sum + 1e-16f), h);
  float acc0[8] = {}, acc1[8] = {};
  int p = e0;
  if (deg <= CAPD) {
    for (; p + 4 <= e1; p += 4) {
      int q = p - e0;
      int s0 = adj[p], s1 = adj[p + 1], s2 = adj[p + 2], s3 = adj[p + 3];
      float w0 = exw[q * 16 + h];
      float w1 = exw[(q + 1) * 16 + h];
      float w2 = exw[(q + 2) * 16 + h];
      float w3 = exw[(q + 3) * 16 + h];
      short8v h0 = *(const short8v*)(hbase + (size_t)s0 * HW + h * CC + coff);
      short8v h1 = *(const short8v*)(hbase + (size_t)s1 * HW + h * CC + coff);
      short8v h2 = *(const short8v*)(hbase + (size_t)s2 * HW + h * CC + coff);
      short8v h3 = *(const short8v*)(hbase + (size_t)s3 * HW + h * CC + coff);
#pragma unroll
      for (int i = 0; i < 8; ++i) {
        acc0[i] = fmaf(w0, bf2f((u16)h0[i]), acc0[i]);
        acc1[i] = fmaf(w1, bf2f((u16)h1[i]), acc1[i]);
        acc0[i] = fmaf(w2, bf2f((u16)h2[i]), acc0[i]);
        acc1[i] = fmaf(w3, bf2f((u16)h3[i]), acc1[i]);
      }
    }
    for (; p < e1; ++p) {
      int q = p - e0;
      int s0 = adj[p];
      float w0 = exw[q * 16 + h];
      short8v h0 = *(const short8v*)(hbase + (size_t)s0 * HW + h * CC + coff);
#pragma unroll
      for (int i = 0; i < 8; ++i) acc0[i] = fmaf(w0, bf2f((u16)h0[i]), acc0[i]);
    }
  } else {  // rare: deg > CAPD, recompute weights past capacity
    const float adh = a_d[node * HH + h];
    for (; p < e1; ++p) {
      int q = p - e0;
      int s0 = adj[p];
      float w0;
      if (q < CAPD) {
        w0 = exw[q * 16 + h];
      } else {
        float a = a_s[s0 * HH + h] + adh;
        a = a > 0.f ? a : 0.2f * a;
        w0 = __expf(a - mxh);
      }
      short8v h0 = *(const short8v*)(hbase + (size_t)s0 * HW + h * CC + coff);
#pragma unroll
      for (int i = 0; i < 8; ++i) acc0[i] = fmaf(w0, bf2f((u16)h0[i]), acc0[i]);
    }
  }
  float accf[8];
#pragma unroll
  for (int i = 0; i < 8; ++i) accf[i] = (acc0[i] + acc1[i]) * ivh;
#pragma unroll
  for (int mk = 4; mk <= 32; mk <<= 1)
#pragma unroll
    for (int i = 0; i < 8; ++i) accf[i] += __shfl_xor(accf[i], mk);
  if (lane < 4) {
#pragma unroll
    for (int i = 0; i < 8; ++i) {
      int c = coff + i;
      float v = accf[i] * (1.f / 16.f) + bias[c];
      v = v > 0.f ? v : (expf(v) - 1.f);
      outp[(size_t)node * OUTC + c] = v;
    }
  }
}

// ---------------------------------------------------------------- launch
extern "C" void kernel_launch(void* const* d_in, const int* in_sizes, int n_in,
                              void* d_out, int out_size, void* d_ws, size_t ws_size,
                              hipStream_t stream) {
  const float* x = (const float*)d_in[0];
  const int* ei = (const int*)d_in[1];
  const float* W1 = (const float*)d_in[2];
  const float* att_src1 = (const float*)d_in[3];
  const float* att_dst1 = (const float*)d_in[4];
  const float* b1 = (const float*)d_in[5];
  const float* W2 = (const float*)d_in[6];
  const float* att_src2 = (const float*)d_in[7];
  const float* att_dst2 = (const float*)d_in[8];
  const float* b2 = (const float*)d_in[9];
  const float* lin1_w = (const float*)d_in[10];
  const float* lin1_b = (const float*)d_in[11];
  const float* lin2_w = (const float*)d_in[12];
  const float* lin2_b = (const float*)d_in[13];
  float* out = (float*)d_out;  // [x_in | x_out | x_self], each N*32

  char* w = (char*)d_ws;
  u16* h12 = (u16*)w;       w += (size_t)NN * HW * 2;      // 40.96 MB
  u16* x_bf = (u16*)w;      w += (size_t)NN * FIN * 2;     // 10.24 MB
  u16* wtc = (u16*)w;       w += (size_t)WT * FIN * 2;     // 0.52 MB
  u16* lt1 = (u16*)w;       w += (size_t)HIDN * FIN * 2;
  u16* lt2 = (u16*)w;       w += (size_t)OUTC * HIDN * 2;
  float* a_sA = (float*)w;  w += (size_t)2 * NN * HH * 4;  // 2.56 MB
  float* a_dA = (float*)w;  w += (size_t)2 * NN * HH * 4;
  int* off1 = (int*)w;      w += (size_t)(NN + 1) * 4;
  int* off2 = (int*)w;      w += (size_t)(NN + 1) * 4;
  int* cur = (int*)w;       w += (size_t)2 * NN * 4;
  int* adj1 = (int*)w;      w += (size_t)EE * 4;
  int* adj2 = (int*)w;      w += (size_t)EE * 4;

  const int EB = (EE + 255) / 256;

  // CSR build
  hipMemsetAsync(cur, 0, (size_t)2 * NN * 4, stream);
  k_hist<<<EB, 256, 0, stream>>>(ei, cur);
  k_scan<<<2, 1024, 0, stream>>>(cur, off1, off2);
  k_scatter<<<EB, 256, 0, stream>>>(ei, cur, adj1, adj2);

  // converts (one launch)
  k_prep<<<3668, 256, 0, stream>>>(x, x_bf, W1, W2, wtc, lin1_w, lt1, lin2_w, lt2);

  // mega GEMM with fused attention scores
  k_gemm_big<<<1256, 256, 0, stream>>>(x_bf, wtc, att_src1, att_dst1,
                                       att_src2, att_dst2, h12, a_sA, a_dA);

  // self path, fully fused
  k_self<<<157, 256, 0, stream>>>(x_bf, lt1, lt2, lin1_b, lin2_b,
                                  out + (size_t)2 * NN * OUTC);

  // fused softmax+aggregation, both convs
  k_edge<<<2 * (NN / 4), 256, 0, stream>>>(adj1, off1, adj2, off2, a_sA, a_dA,
                                           h12, b1, b2, out);
}

// Round 7
// 291.576 us; speedup vs baseline: 2.3030x; 1.0146x over previous
//
#include <hip/hip_runtime.h>
#include <math.h>

#define NN 20000
#define EE 400000
#define FIN 256
#define HH 16
#define CC 32
#define HC 512    // H*C per conv
#define HW 1024   // h12 row width (conv1 | conv2)
#define HIDN 128
#define OUTC 32
#define WT 1024   // wtc rows (W1^T | W2^T)
#define CAPD 64   // per-node LDS edge capacity (deg ~ Poisson(20), P(>64)~1e-16)

typedef unsigned short u16;
typedef __attribute__((ext_vector_type(8))) short short8v;
typedef __attribute__((ext_vector_type(4))) float f32x4;

__device__ inline u16 f2bf(float f) {
  unsigned u = __builtin_bit_cast(unsigned, f);
  unsigned r = (u + 0x7fffu + ((u >> 16) & 1u)) >> 16;
  return (u16)r;
}
__device__ inline float bf2f(u16 b) {
  unsigned u = ((unsigned)b) << 16;
  return __builtin_bit_cast(float, u);
}

__device__ __forceinline__ void gload16(const u16* g, u16* l) {
  __builtin_amdgcn_global_load_lds(
      (const __attribute__((address_space(1))) unsigned int*)g,
      (__attribute__((address_space(3))) unsigned int*)l, 16, 0, 0);
}

// ------------------------------------------- merged converts + edge histogram
// [0,2500): x->bf16 ; [2500,3524): wtc (W1^T|W2^T) ; [3524,3652): lt1 ;
// [3652,3668): lt2 ; [3668,5231): histogram
__global__ void k_prep_hist(const float* __restrict__ x, u16* __restrict__ xb,
                            const float* __restrict__ W1, const float* __restrict__ W2,
                            u16* __restrict__ wtc,
                            const float* __restrict__ L1, u16* __restrict__ lt1,
                            const float* __restrict__ L2, u16* __restrict__ lt2,
                            const int* __restrict__ ei, int* __restrict__ cur) {
  int b = blockIdx.x, t = threadIdx.x;
  if (b < 2500) {
    int i = b * 256 + t;
    float4 v0 = ((const float4*)x)[i * 2];
    float4 v1 = ((const float4*)x)[i * 2 + 1];
    short8v o;
    o[0] = (short)f2bf(v0.x); o[1] = (short)f2bf(v0.y);
    o[2] = (short)f2bf(v0.z); o[3] = (short)f2bf(v0.w);
    o[4] = (short)f2bf(v1.x); o[5] = (short)f2bf(v1.y);
    o[6] = (short)f2bf(v1.z); o[7] = (short)f2bf(v1.w);
    *(short8v*)(xb + (size_t)i * 8) = o;
  } else if (b < 3524) {
    int i = (b - 2500) * 256 + t;   // [1024][256]
    int n = i >> 8, k = i & 255;
    wtc[i] = f2bf(n < 512 ? W1[k * HC + n] : W2[k * HC + (n - 512)]);
  } else if (b < 3652) {
    int i = (b - 3524) * 256 + t;   // [128][256]
    int n = i >> 8, k = i & 255;
    lt1[i] = f2bf(L1[k * HIDN + n]);
  } else if (b < 3668) {
    int i = (b - 3652) * 256 + t;   // [32][128]
    int n = i >> 7, k = i & 127;
    lt2[i] = f2bf(L2[k * OUTC + n]);
  } else {
    int e = (b - 3668) * 256 + t;
    if (e < EE) {
      atomicAdd(&cur[ei[EE + e]], 1);       // conv1 aggregates at row1
      atomicAdd(&cur[NN + ei[e]], 1);       // conv2 aggregates at row0
    }
  }
}

__device__ void scan_one(int* cur, int* off, int* part) {
  const int t = threadIdx.x;
  const int CHK = 20;
  int base = t * CHK;
  int loc[CHK];
  int s = 0;
#pragma unroll
  for (int i = 0; i < CHK; ++i) {
    int idx = base + i;
    int v = (idx < NN) ? cur[idx] : 0;
    loc[i] = s;
    s += v;
  }
  part[t] = s;
  __syncthreads();
  for (int d = 1; d < 1024; d <<= 1) {
    int v2 = (t >= d) ? part[t - d] : 0;
    __syncthreads();
    part[t] += v2;
    __syncthreads();
  }
  int cbase = part[t] - s;
#pragma unroll
  for (int i = 0; i < CHK; ++i) {
    int idx = base + i;
    if (idx < NN) {
      int o = cbase + loc[i];
      off[idx] = o;
      cur[idx] = o;
    }
  }
  if (t == 1023) off[NN] = part[1023];
}

__global__ __launch_bounds__(1024) void k_scan(int* cur, int* off1, int* off2) {
  __shared__ int part[1024];
  if (blockIdx.x == 0) scan_one(cur, off1, part);
  else                 scan_one(cur + NN, off2, part);
}

// adj lists + cross-permutation: xlA[p1]=p2 (conv1 dst-pos -> src-pos),
// xlB[p2]=p1 (conv2 dst-pos -> src-pos).
__global__ void k_scatter(const int* __restrict__ ei, int* cur,
                          int* __restrict__ adj1, int* __restrict__ adj2,
                          int* __restrict__ xlA, int* __restrict__ xlB) {
  int e = blockIdx.x * 256 + threadIdx.x;
  if (e < EE) {
    int s1 = ei[e], d1 = ei[EE + e];
    int p1 = atomicAdd(&cur[d1], 1);
    adj1[p1] = s1;                      // conv1: message source = row0
    int p2 = atomicAdd(&cur[NN + s1], 1);
    adj2[p2] = d1;                      // conv2: message source = row1
    xlA[p1] = p2;
    xlB[p2] = p1;
  }
}

// ------------------------- mega kernel: GEMM (+fused a_s/a_d) | self MLP path
// blocks [0,1256): h12 = x@ [W1|W2]^T ; [1256,1413): x_self
__global__ __launch_bounds__(256) void k_mega(const u16* __restrict__ A,
                                              const u16* __restrict__ Bt,
                                              const float* __restrict__ as1,
                                              const float* __restrict__ ad1,
                                              const float* __restrict__ as2,
                                              const float* __restrict__ ad2,
                                              u16* __restrict__ h12,
                                              float* __restrict__ a_sA,
                                              float* __restrict__ a_dA,
                                              const u16* __restrict__ lt1,
                                              const u16* __restrict__ lt2,
                                              const float* __restrict__ lin1_b,
                                              const float* __restrict__ lin2_b,
                                              float* __restrict__ out3) {
  __shared__ u16 smem[128 * 136];
  u16* As = smem;
  u16* Bs = smem + 128 * 64;
  const int t = threadIdx.x;
  const int lane = t & 63, wave = t >> 6;
  const int wr = (wave >> 1) * 64, wc = (wave & 1) * 64;
  const int l15 = lane & 15, l4 = lane >> 4;
  const int rloc = lane >> 3;
  const int kc_src = (lane & 7) ^ rloc;
  const int K = FIN;

  if (blockIdx.x < 1256) {
    // ---------------- GEMM path
    const int hw = blockIdx.x;
    const int logical = (hw & 7) * 157 + (hw >> 3);   // XCD-chunked
    const int bm = (logical >> 3) * 128, bn = logical & 7;

    f32x4 acc[4][4] = {};
    for (int k0 = 0; k0 < K; k0 += 64) {
      __syncthreads();
#pragma unroll
      for (int q = 0; q < 4; ++q) {
        const int rblk = q * 4 + wave;
        const int r = rblk * 8 + rloc;
        gload16(A + (size_t)(bm + r) * K + k0 + kc_src * 8, As + rblk * 512);
        gload16(Bt + (size_t)(bn * 128 + r) * K + k0 + kc_src * 8, Bs + rblk * 512);
      }
      __syncthreads();
#pragma unroll
      for (int kh = 0; kh < 2; ++kh) {
        const int kc = kh * 4 + l4;
        short8v af[4], bfr[4];
#pragma unroll
        for (int i = 0; i < 4; ++i) {
          int row = wr + i * 16 + l15;
          af[i] = *(const short8v*)(As + row * 64 + (kc ^ (row & 7)) * 8);
        }
#pragma unroll
        for (int j = 0; j < 4; ++j) {
          int row = wc + j * 16 + l15;
          bfr[j] = *(const short8v*)(Bs + row * 64 + (kc ^ (row & 7)) * 8);
        }
#pragma unroll
        for (int i = 0; i < 4; ++i)
#pragma unroll
          for (int j = 0; j < 4; ++j)
            acc[i][j] = __builtin_amdgcn_mfma_f32_16x16x32_bf16(af[i], bfr[j], acc[i][j], 0, 0, 0);
      }
    }

    const int conv = bn >> 2;
#pragma unroll
    for (int i = 0; i < 4; ++i)
#pragma unroll
      for (int j = 0; j < 4; ++j)
#pragma unroll
        for (int r = 0; r < 4; ++r) {
          int row = bm + wr + i * 16 + l4 * 4 + r;
          if (row >= NN) continue;
          int colb = bn * 128 + wc + j * 16 + l15;
          h12[(size_t)row * HW + colb] = f2bf(acc[i][j][r]);
        }

    float asv[4], adv[4];
#pragma unroll
    for (int j = 0; j < 4; ++j) {
      int lc = (bn & 3) * 128 + wc + j * 16 + l15;
      int hh = lc >> 5, c = lc & 31;
      asv[j] = (conv ? as2 : as1)[hh * CC + c];
      adv[j] = (conv ? ad2 : ad1)[hh * CC + c];
    }
    const int hA = (bn & 3) * 4 + (wc >> 5);
    float* aS = a_sA + (size_t)conv * NN * HH;
    float* aD = a_dA + (size_t)conv * NN * HH;
#pragma unroll
    for (int i = 0; i < 4; ++i)
#pragma unroll
      for (int r = 0; r < 4; ++r) {
        float sAs = acc[i][0][r] * asv[0] + acc[i][1][r] * asv[1];
        float sAd = acc[i][0][r] * adv[0] + acc[i][1][r] * adv[1];
        float sBs = acc[i][2][r] * asv[2] + acc[i][3][r] * asv[3];
        float sBd = acc[i][2][r] * adv[2] + acc[i][3][r] * adv[3];
#pragma unroll
        for (int m = 1; m < 16; m <<= 1) {
          sAs += __shfl_xor(sAs, m);
          sAd += __shfl_xor(sAd, m);
          sBs += __shfl_xor(sBs, m);
          sBd += __shfl_xor(sBd, m);
        }
        int row = bm + wr + i * 16 + l4 * 4 + r;
        if (l15 == 0 && row < NN) {
          *(float2*)(aS + (size_t)row * HH + hA) = make_float2(sAs, sBs);
          *(float2*)(aD + (size_t)row * HH + hA) = make_float2(sAd, sBd);
        }
      }
  } else {
    // ---------------- self path
    const int bm = (blockIdx.x - 1256) * 128;
    f32x4 acc[4][4] = {};
    for (int k0 = 0; k0 < K; k0 += 64) {
      __syncthreads();
#pragma unroll
      for (int q = 0; q < 4; ++q) {
        const int rblk = q * 4 + wave;
        const int r = rblk * 8 + rloc;
        gload16(A + (size_t)(bm + r) * K + k0 + kc_src * 8, As + rblk * 512);
        gload16(lt1 + (size_t)r * K + k0 + kc_src * 8, Bs + rblk * 512);
      }
      __syncthreads();
#pragma unroll
      for (int kh = 0; kh < 2; ++kh) {
        const int kc = kh * 4 + l4;
        short8v af[4], bfr[4];
#pragma unroll
        for (int i = 0; i < 4; ++i) {
          int row = wr + i * 16 + l15;
          af[i] = *(const short8v*)(As + row * 64 + (kc ^ (row & 7)) * 8);
        }
#pragma unroll
        for (int j = 0; j < 4; ++j) {
          int row = wc + j * 16 + l15;
          bfr[j] = *(const short8v*)(Bs + row * 64 + (kc ^ (row & 7)) * 8);
        }
#pragma unroll
        for (int i = 0; i < 4; ++i)
#pragma unroll
          for (int j = 0; j < 4; ++j)
            acc[i][j] = __builtin_amdgcn_mfma_f32_16x16x32_bf16(af[i], bfr[j], acc[i][j], 0, 0, 0);
      }
    }
    __syncthreads();
#pragma unroll
    for (int i = 0; i < 4; ++i)
#pragma unroll
      for (int j = 0; j < 4; ++j)
#pragma unroll
        for (int r = 0; r < 4; ++r) {
          int row = wr + i * 16 + l4 * 4 + r;
          int col = wc + j * 16 + l15;
          float v = acc[i][j][r] + lin1_b[col];
          v = v > 0.f ? v : (expf(v) - 1.f);
          smem[row * 136 + col] = f2bf(v);
        }
    __syncthreads();
    f32x4 acc2[2][2] = {};
#pragma unroll
    for (int kk = 0; kk < 4; ++kk) {
      short8v af[2], bfr[2];
#pragma unroll
      for (int i = 0; i < 2; ++i)
        af[i] = *(const short8v*)(smem + (wave * 32 + i * 16 + l15) * 136 + kk * 32 + l4 * 8);
#pragma unroll
      for (int j = 0; j < 2; ++j)
        bfr[j] = *(const short8v*)(lt2 + (size_t)(j * 16 + l15) * 128 + kk * 32 + l4 * 8);
#pragma unroll
      for (int i = 0; i < 2; ++i)
#pragma unroll
        for (int j = 0; j < 2; ++j)
          acc2[i][j] = __builtin_amdgcn_mfma_f32_16x16x32_bf16(af[i], bfr[j], acc2[i][j], 0, 0, 0);
    }
#pragma unroll
    for (int i = 0; i < 2; ++i)
#pragma unroll
      for (int j = 0; j < 2; ++j)
#pragma unroll
        for (int r = 0; r < 4; ++r) {
          int row = bm + wave * 32 + i * 16 + l4 * 4 + r;
          int col = j * 16 + l15;
          if (row < NN) {
            float v = acc2[i][j][r] + lin2_b[col];
            v = v > 0.f ? v : (expf(v) - 1.f);
            out3[(size_t)row * OUTC + col] = v;
          }
        }
  }
}

// --------------- phase A: dst-grouped softmax -> coef (bf16, /16 folded) at
// src-CSR positions via xl.  Both convs, 1 wave/node, independent waves.
__global__ __launch_bounds__(256) void k_phaseA(const int* __restrict__ adj1,
                                                const int* __restrict__ off1,
                                                const int* __restrict__ xlA,
                                                const int* __restrict__ adj2,
                                                const int* __restrict__ off2,
                                                const int* __restrict__ xlB,
                                                const float* __restrict__ a_sA,
                                                const float* __restrict__ a_dA,
                                                u16* __restrict__ coefA,
                                                u16* __restrict__ coefB) {
  __shared__ float exs[4][CAPD * 16];
  const int wv = threadIdx.x >> 6, lane = threadIdx.x & 63;
  const int gid = blockIdx.x * 4 + wv;
  const int conv = gid >= NN;
  const int node = gid - conv * NN;
  const int* __restrict__ adj = conv ? adj2 : adj1;
  const int* __restrict__ off = conv ? off2 : off1;
  const int* __restrict__ xl = conv ? xlB : xlA;
  u16* __restrict__ coef = conv ? coefB : coefA;
  const float* __restrict__ a_s = a_sA + (size_t)conv * NN * HH;
  const float* __restrict__ a_d = a_dA + (size_t)conv * NN * HH;
  float* exw = exs[wv];
  const int e0 = off[node], e1 = off[node + 1];
  if (e0 == e1) return;

  const int ha = lane & 15, j = lane >> 4;
  const float adh = a_d[node * HH + ha];
  float mx = -INFINITY;
  for (int p = e0 + j; p < e1; p += 4) {
    int s = adj[p];
    float a = a_s[s * HH + ha] + adh;
    a = a > 0.f ? a : 0.2f * a;
    int q = p - e0;
    if (q < CAPD) exw[q * 16 + ha] = a;
    mx = fmaxf(mx, a);
  }
  mx = fmaxf(mx, __shfl_xor(mx, 16));
  mx = fmaxf(mx, __shfl_xor(mx, 32));
  float sum = 0.f;
  for (int p = e0 + j; p < e1; p += 4) {
    int q = p - e0;
    float a;
    if (q < CAPD) {
      a = exw[q * 16 + ha];
    } else {
      int s = adj[p];
      a = a_s[s * HH + ha] + adh;
      a = a > 0.f ? a : 0.2f * a;
    }
    float e = __expf(a - mx);
    if (q < CAPD) exw[q * 16 + ha] = e;
    sum += e;
  }
  sum += __shfl_xor(sum, 16);
  sum += __shfl_xor(sum, 32);
  const float inv16 = 1.f / ((sum + 1e-16f) * 16.f);
  // write coef to src-CSR positions
  for (int p = e0 + j; p < e1; p += 4) {
    int q = p - e0;
    float e;
    if (q < CAPD) {
      e = exw[q * 16 + ha];
    } else {
      int s = adj[p];
      float a = a_s[s * HH + ha] + adh;
      a = a > 0.f ? a : 0.2f * a;
      e = __expf(a - mx);
    }
    coef[(size_t)xl[p] * 16 + ha] = f2bf(e * inv16);
  }
}

// --------------- scatterv: src-grouped, sequential. v[q][c] = sum_h coef*h
__global__ __launch_bounds__(256) void k_scatterv(const int* __restrict__ offS,
                                                  const u16* __restrict__ coef,
                                                  const u16* __restrict__ h12,
                                                  int convoff,
                                                  u16* __restrict__ vbuf) {
  __shared__ u16 hs[4][512];
  const int wv = threadIdx.x >> 6, lane = threadIdx.x & 63;
  const int s = blockIdx.x * 4 + wv;
  const int e0 = offS[s], e1 = offS[s + 1];
  if (e0 == e1) return;
  // stage h row (512 bf16 = 1 KB, one coalesced load)
  const u16* hp = h12 + (size_t)s * HW + convoff;
  *(short8v*)&hs[wv][lane * 8] = *(const short8v*)(hp + lane * 8);
  __builtin_amdgcn_wave_barrier();
  __asm__ volatile("" ::: "memory");
  const int c = lane & 31, ep = lane >> 5;
  float hreg[16];
#pragma unroll
  for (int h = 0; h < 16; ++h) hreg[h] = bf2f(hs[wv][h * 32 + c]);
  for (int q = e0 + ep; q < e1; q += 2) {
    short8v c0 = *(const short8v*)(coef + (size_t)q * 16);
    short8v c1 = *(const short8v*)(coef + (size_t)q * 16 + 8);
    float v = 0.f;
#pragma unroll
    for (int h = 0; h < 8; ++h) v = fmaf(bf2f((u16)c0[h]), hreg[h], v);
#pragma unroll
    for (int h = 0; h < 8; ++h) v = fmaf(bf2f((u16)c1[h]), hreg[h + 8], v);
    vbuf[(size_t)q * 32 + c] = f2bf(v);
  }
}

// --------------- pass2: dst-grouped gather of v (64B/edge), sum, bias+elu
__global__ __launch_bounds__(256) void k_pass2(const int* __restrict__ offD,
                                               const int* __restrict__ xl,
                                               const u16* __restrict__ vbuf,
                                               const float* __restrict__ bias,
                                               float* __restrict__ outp) {
  const int wv = threadIdx.x >> 6, lane = threadIdx.x & 63;
  const int d = blockIdx.x * 4 + wv;
  const int c = lane & 31, ep = lane >> 5;
  const int e0 = offD[d], e1 = offD[d + 1];
  float a0 = 0.f, a1 = 0.f;
  int p = e0 + ep;
  for (; p + 2 < e1; p += 4) {
    int cs0 = xl[p], cs1 = xl[p + 2];
    a0 += bf2f(vbuf[(size_t)cs0 * 32 + c]);
    a1 += bf2f(vbuf[(size_t)cs1 * 32 + c]);
  }
  if (p < e1) a0 += bf2f(vbuf[(size_t)xl[p] * 32 + c]);
  float acc = a0 + a1;
  acc += __shfl_xor(acc, 32);
  if (lane < 32) {
    float v = acc + bias[c];
    v = v > 0.f ? v : (expf(v) - 1.f);
    outp[(size_t)d * OUTC + c] = v;
  }
}

// ---------------------------------------------------------------- launch
extern "C" void kernel_launch(void* const* d_in, const int* in_sizes, int n_in,
                              void* d_out, int out_size, void* d_ws, size_t ws_size,
                              hipStream_t stream) {
  const float* x = (const float*)d_in[0];
  const int* ei = (const int*)d_in[1];
  const float* W1 = (const float*)d_in[2];
  const float* att_src1 = (const float*)d_in[3];
  const float* att_dst1 = (const float*)d_in[4];
  const float* b1 = (const float*)d_in[5];
  const float* W2 = (const float*)d_in[6];
  const float* att_src2 = (const float*)d_in[7];
  const float* att_dst2 = (const float*)d_in[8];
  const float* b2 = (const float*)d_in[9];
  const float* lin1_w = (const float*)d_in[10];
  const float* lin1_b = (const float*)d_in[11];
  const float* lin2_w = (const float*)d_in[12];
  const float* lin2_b = (const float*)d_in[13];
  float* out = (float*)d_out;  // [x_in | x_out | x_self], each N*32

  char* w = (char*)d_ws;
  u16* h12 = (u16*)w;       w += (size_t)NN * HW * 2;      // 40.96 MB
  u16* x_bf = (u16*)w;      w += (size_t)NN * FIN * 2;     // 10.24 MB
  u16* wtc = (u16*)w;       w += (size_t)WT * FIN * 2;     // 0.52 MB
  u16* lt1 = (u16*)w;       w += (size_t)HIDN * FIN * 2;
  u16* lt2 = (u16*)w;       w += (size_t)OUTC * HIDN * 2;
  u16* coefA = (u16*)w;     w += (size_t)EE * HH * 2;      // 12.8 MB
  u16* coefB = (u16*)w;     w += (size_t)EE * HH * 2;      // 12.8 MB
  u16* vbuf = (u16*)w;      w += (size_t)EE * OUTC * 2;    // 25.6 MB (shared)
  float* a_sA = (float*)w;  w += (size_t)2 * NN * HH * 4;  // 2.56 MB
  float* a_dA = (float*)w;  w += (size_t)2 * NN * HH * 4;
  int* off1 = (int*)w;      w += (size_t)(NN + 1) * 4;
  int* off2 = (int*)w;      w += (size_t)(NN + 1) * 4;
  int* cur = (int*)w;       w += (size_t)2 * NN * 4;
  int* adj1 = (int*)w;      w += (size_t)EE * 4;
  int* adj2 = (int*)w;      w += (size_t)EE * 4;
  int* xlA = (int*)w;       w += (size_t)EE * 4;
  int* xlB = (int*)w;       w += (size_t)EE * 4;

  const int EB = (EE + 255) / 256;  // 1563

  // CSR build + converts
  hipMemsetAsync(cur, 0, (size_t)2 * NN * 4, stream);
  k_prep_hist<<<3668 + EB, 256, 0, stream>>>(x, x_bf, W1, W2, wtc, lin1_w, lt1,
                                             lin2_w, lt2, ei, cur);
  k_scan<<<2, 1024, 0, stream>>>(cur, off1, off2);
  k_scatter<<<EB, 256, 0, stream>>>(ei, cur, adj1, adj2, xlA, xlB);

  // mega GEMM (h12 + fused a_s/a_d) | self path
  k_mega<<<1256 + 157, 256, 0, stream>>>(x_bf, wtc, att_src1, att_dst1,
                                         att_src2, att_dst2, h12, a_sA, a_dA,
                                         lt1, lt2, lin1_b, lin2_b,
                                         out + (size_t)2 * NN * OUTC);

  // edge pipeline
  k_phaseA<<<2 * (NN / 4), 256, 0, stream>>>(adj1, off1, xlA, adj2, off2, xlB,
                                             a_sA, a_dA, coefA, coefB);
  // conv1: src-grouping = off2 (row0), h half 0
  k_scatterv<<<NN / 4, 256, 0, stream>>>(off2, coefA, h12, 0, vbuf);
  k_pass2<<<NN / 4, 256, 0, stream>>>(off1, xlA, vbuf, b1, out);
  // conv2: src-grouping = off1 (row1), h half 1
  k_scatterv<<<NN / 4, 256, 0, stream>>>(off1, coefB, h12, HC, vbuf);
  k_pass2<<<NN / 4, 256, 0, stream>>>(off2, xlB, vbuf, b2, out + (size_t)NN * OUTC);
}